// Round 9
// baseline (303.368 us; speedup 1.0000x reference)
//
#include <hip/hip_runtime.h>
#include <hip/hip_fp16.h>
#include <math.h>

#define FIN 256
#define HID 128
#define NCLS 40
#define ZPB 64   // fp8 Z row stride in bytes (one cache line)
#define BKT_SHIFT 9
#define BKT_SZ 512
#define CHUNK 2048

typedef __attribute__((ext_vector_type(8))) short short8_t;
typedef __attribute__((ext_vector_type(8))) _Float16 half8_t;
typedef __attribute__((ext_vector_type(4))) float f32x4;
typedef __attribute__((ext_vector_type(2))) float f32x2;

static __device__ __forceinline__ ushort f2bf(float f) {
    unsigned u = __float_as_uint(f);
    u += 0x7FFF + ((u >> 16) & 1);
    return (ushort)(u >> 16);
}

// packed edge: src (17 bits) << 15 | top-15-bits-of-fp32-weight (sign0+exp8+mant6)
static __device__ __forceinline__ unsigned pack_ew(int s, float w) {
    return ((unsigned)s << 15) | (__float_as_uint(w) >> 17);
}

// ---------------- CSR build: hist + node-level scan ----------------

__global__ void k_zero_int(int* p, int n) {
    int i = blockIdx.x * blockDim.x + threadIdx.x;
    if (i < n) p[i] = 0;
}

__global__ void k_hist(const int* __restrict__ dst, int E, int* __restrict__ cnt) {
    int e = blockIdx.x * blockDim.x + threadIdx.x;
    if (e < E) atomicAdd(&cnt[dst[e]], 1);
}

__global__ __launch_bounds__(1024) void k_scan1(const int* __restrict__ cnt, int* __restrict__ off,
                                                int* __restrict__ bsum, int n) {
    __shared__ int sm[1024];
    int t = threadIdx.x;
    int i = blockIdx.x * 1024 + t;
    int v = (i < n) ? cnt[i] : 0;
    sm[t] = v;
    __syncthreads();
    for (int o = 1; o < 1024; o <<= 1) {
        int u = (t >= o) ? sm[t - o] : 0;
        __syncthreads();
        sm[t] += u;
        __syncthreads();
    }
    if (i < n) off[i] = sm[t];
    if (t == 1023) bsum[blockIdx.x] = sm[1023];
}

__global__ void k_scan2(int* __restrict__ bsum, int nb) {
    int lane = threadIdx.x;
    int v0 = (lane < nb) ? bsum[lane] : 0;
    int v1 = (64 + lane < nb) ? bsum[64 + lane] : 0;
    int o0 = v0, o1 = v1;
    for (int o = 1; o < 64; o <<= 1) {
        int t = __shfl_up(v0, o);
        if (lane >= o) v0 += t;
    }
    int tot0 = __shfl(v0, 63);
    for (int o = 1; o < 64; o <<= 1) {
        int t = __shfl_up(v1, o);
        if (lane >= o) v1 += t;
    }
    v1 += tot0;
    if (lane < nb) bsum[lane] = v0 - o0;
    if (64 + lane < nb) bsum[64 + lane] = v1 - o1;
}

__global__ void k_scan3(int* __restrict__ off, const int* __restrict__ cnt,
                        const int* __restrict__ bsum, float* __restrict__ dinv, int n) {
    int i = blockIdx.x * blockDim.x + threadIdx.x;
    if (i < n) {
        int excl = off[i] - cnt[i] + bsum[i >> 10];
        off[i] = excl;
        dinv[i] = rsqrtf((float)(cnt[i] + 1));
    }
}

__global__ void k_binit(const int* __restrict__ off, int* __restrict__ boff,
                        int* __restrict__ bcur, int n, int E, int nbk) {
    int t = threadIdx.x;
    if (t <= nbk) {
        int idx = t << BKT_SHIFT;
        int v = (idx >= n) ? E : off[idx];
        boff[t] = v;
        if (t < nbk) bcur[t] = v;
    }
}

// ---------------- phase 1: bucketize edges by dst>>9 ----------------

__global__ __launch_bounds__(256) void k_bucketize(const int* __restrict__ src,
                                                   const int* __restrict__ dst, int E,
                                                   int* __restrict__ bcur,
                                                   int2* __restrict__ ebkt, int nbk) {
    __shared__ int hist[256];
    __shared__ int scanb[256];
    __shared__ int base[256];
    __shared__ int gbase[256];
    __shared__ int2 stage[CHUNK];
    int t = threadIdx.x;
    int e0 = blockIdx.x * CHUNK;
    int cntc = min(CHUNK, E - e0);
    hist[t] = 0;
    __syncthreads();

    int s_[8], d_[8], bk_[8], rk_[8];
#pragma unroll
    for (int i = 0; i < 8; i++) {
        int j = t + i * 256;
        if (j < cntc) {
            int s = src[e0 + j], d = dst[e0 + j];
            s_[i] = s; d_[i] = d;
            bk_[i] = d >> BKT_SHIFT;
            rk_[i] = atomicAdd(&hist[bk_[i]], 1);
        } else {
            bk_[i] = -1;
        }
    }
    __syncthreads();

    scanb[t] = hist[t];
    __syncthreads();
    for (int o = 1; o < 256; o <<= 1) {
        int u = (t >= o) ? scanb[t - o] : 0;
        __syncthreads();
        scanb[t] += u;
        __syncthreads();
    }
    base[t] = scanb[t] - hist[t];
    if (t < nbk && hist[t] > 0) gbase[t] = atomicAdd(&bcur[t], hist[t]);
    __syncthreads();

#pragma unroll
    for (int i = 0; i < 8; i++) {
        if (bk_[i] >= 0) stage[base[bk_[i]] + rk_[i]] = make_int2(s_[i], d_[i]);
    }
    __syncthreads();

#pragma unroll
    for (int i = 0; i < 8; i++) {
        int j = t + i * 256;
        if (j < cntc) {
            int2 e = stage[j];
            int bk = e.y >> BKT_SHIFT;
            ebkt[gbase[bk] + (j - base[bk])] = e;
        }
    }
}

// ---------------- phase 2: within-bucket placement; pack (src, weight) ----------------

__global__ __launch_bounds__(512) void k_sortbkt(const int2* __restrict__ ebkt,
                                                 const int* __restrict__ boff,
                                                 const int* __restrict__ off,
                                                 const float* __restrict__ dinv,
                                                 unsigned* __restrict__ eew, int n) {
    __shared__ int cur[BKT_SZ];
    __shared__ float ldin[BKT_SZ];
    int b = blockIdx.x, t = threadIdx.x;
    int n0 = b << BKT_SHIFT;
    int nn = min(BKT_SZ, n - n0);
    for (int i = t; i < nn; i += 512) {
        cur[i] = off[n0 + i];
        ldin[i] = dinv[n0 + i];
    }
    __syncthreads();
    int e0 = boff[b], e1 = boff[b + 1];
    for (int e = e0 + t; e < e1; e += 512) {
        int2 ed = ebkt[e];
        int s = ed.x, dl = ed.y - n0;
        float w = dinv[s] * ldin[dl];
        int pos = atomicAdd(&cur[dl], 1);
        eew[pos] = pack_ew(s, w);
    }
}

// ---------------- weight conversions ----------------

__global__ void k_w1_cvt(const float* __restrict__ W1, ushort* __restrict__ Wt) {
    int idx = blockIdx.x * 256 + threadIdx.x;  // 128*256
    int c = idx >> 8, k = idx & 255;
    Wt[idx] = f2bf(W1[(size_t)k * HID + c]);
}

__global__ void k_w2_cvt(const float* __restrict__ W2, __half* __restrict__ W2t) {
    int idx = blockIdx.x * 256 + threadIdx.x;  // 48*128
    int c = idx >> 7, k = idx & 127;
    W2t[idx] = __float2half((c < NCLS) ? W2[(size_t)k * NCLS + c] : 0.f);
}

// ---------------- GEMM1 (MFMA bf16): H8 = fp8(X @ W1) ----------------

__global__ __launch_bounds__(256) void k_gemm1(const float* __restrict__ X,
                                               const ushort* __restrict__ Wt,
                                               unsigned char* __restrict__ H8, int M) {
    __shared__ uint4 wlds[128 * 32];  // 64 KB; reused as f32 staging in epilogue
    int tid = threadIdx.x;
    const uint4* wg = (const uint4*)Wt;
#pragma unroll
    for (int i = 0; i < 16; i++) {
        int e = tid + i * 256;
        int r = e >> 5, ch = e & 31;
        wlds[r * 32 + (ch ^ (r & 7))] = wg[e];
    }
    __syncthreads();

    int wid = tid >> 6, lane = tid & 63;
    int q = lane & 15, kg = lane >> 4;
    int grow_in = blockIdx.x * 64 + wid * 16 + q;
    int lrow = min(grow_in, M - 1);
    const float* xr = X + (size_t)lrow * FIN;

    f32x4 acc[8];
#pragma unroll
    for (int c = 0; c < 8; c++) acc[c] = (f32x4){0.f, 0.f, 0.f, 0.f};

#pragma unroll
    for (int kt = 0; kt < 8; kt++) {
        int k0 = kt * 32 + kg * 8;
        float4 f0 = *(const float4*)(xr + k0);
        float4 f1 = *(const float4*)(xr + k0 + 4);
        unsigned r0, r1, r2, r3;
        asm("v_cvt_pk_bf16_f32 %0, %1, %2" : "=v"(r0) : "v"(f0.x), "v"(f0.y));
        asm("v_cvt_pk_bf16_f32 %0, %1, %2" : "=v"(r1) : "v"(f0.z), "v"(f0.w));
        asm("v_cvt_pk_bf16_f32 %0, %1, %2" : "=v"(r2) : "v"(f1.x), "v"(f1.y));
        asm("v_cvt_pk_bf16_f32 %0, %1, %2" : "=v"(r3) : "v"(f1.z), "v"(f1.w));
        union { uint4 u; short8_t s; } cv;
        cv.u = make_uint4(r0, r1, r2, r3);
        short8_t a = cv.s;
        int ch = kt * 4 + kg;
#pragma unroll
        for (int c = 0; c < 8; c++) {
            int col = c * 16 + q;
            short8_t b = *(const short8_t*)&wlds[col * 32 + (ch ^ (col & 7))];
            acc[c] = __builtin_amdgcn_mfma_f32_16x16x32_bf16(a, b, acc[c], 0, 0, 0);
        }
    }

    __syncthreads();
    float* st = (float*)wlds;  // [64][132]
#pragma unroll
    for (int c = 0; c < 8; c++) {
        int col = c * 16 + q;
#pragma unroll
        for (int i = 0; i < 4; i++) {
            int lr = wid * 16 + kg * 4 + i;
            st[lr * 132 + col] = acc[c][i];
        }
    }
    __syncthreads();
    int orow = tid >> 2, seg = tid & 3;
    int grow = blockIdx.x * 64 + orow;
    if (grow < M) {
        const float* sp = st + orow * 132 + seg * 32;
        unsigned u[8];
#pragma unroll
        for (int k = 0; k < 8; k++) {
            int p = 0;
            p = __builtin_amdgcn_cvt_pk_fp8_f32(sp[4 * k + 0], sp[4 * k + 1], p, false);
            p = __builtin_amdgcn_cvt_pk_fp8_f32(sp[4 * k + 2], sp[4 * k + 3], p, true);
            u[k] = (unsigned)p;
        }
        uint4* op = (uint4*)(H8 + (size_t)grow * HID + seg * 32);
        op[0] = make_uint4(u[0], u[1], u[2], u[3]);
        op[1] = make_uint4(u[4], u[5], u[6], u[7]);
    }
}

// ---------------- agg1: H2 = fp16(relu(b1 + sum w*H8[s])) ----------------
// one wave/node; 4x16-lane groups; group g strides edges g, g+4, ... (broadcast loads)

__global__ __launch_bounds__(256) void k_agg1(const unsigned char* __restrict__ H8,
                                              const unsigned* __restrict__ eew,
                                              const int* __restrict__ off,
                                              const int* __restrict__ cnt,
                                              const float* __restrict__ dinv,
                                              const float* __restrict__ b1,
                                              __half* __restrict__ H2, int n) {
    int node = blockIdx.x * 4 + (threadIdx.x >> 6);
    int lane = threadIdx.x & 63;
    if (node >= n) return;
    int q = lane & 15, g = lane >> 4;
    float di = dinv[node];
    int start = off[node], ne = cnt[node];

    float acc[8] = {0.f, 0.f, 0.f, 0.f, 0.f, 0.f, 0.f, 0.f};

    // self-loop (group 0 only)
    if (g == 0) {
        uint2 v = *(const uint2*)(H8 + (size_t)node * HID + q * 8);
        float wv = di * di;
        f32x2 f;
        f = __builtin_amdgcn_cvt_pk_f32_fp8((int)v.x, false);
        acc[0] = f[0] * wv; acc[1] = f[1] * wv;
        f = __builtin_amdgcn_cvt_pk_f32_fp8((int)v.x, true);
        acc[2] = f[0] * wv; acc[3] = f[1] * wv;
        f = __builtin_amdgcn_cvt_pk_f32_fp8((int)v.y, false);
        acc[4] = f[0] * wv; acc[5] = f[1] * wv;
        f = __builtin_amdgcn_cvt_pk_f32_fp8((int)v.y, true);
        acc[6] = f[0] * wv; acc[7] = f[1] * wv;
    }

#pragma unroll 2
    for (int j = g; j < ne; j += 4) {
        unsigned u = __builtin_nontemporal_load(eew + start + j);
        int s = (int)(u >> 15);
        float wv = __uint_as_float((u & 0x7FFFu) << 17);
        uint2 v = *(const uint2*)(H8 + (size_t)s * HID + q * 8);
        f32x2 f;
        f = __builtin_amdgcn_cvt_pk_f32_fp8((int)v.x, false);
        acc[0] = fmaf(f[0], wv, acc[0]); acc[1] = fmaf(f[1], wv, acc[1]);
        f = __builtin_amdgcn_cvt_pk_f32_fp8((int)v.x, true);
        acc[2] = fmaf(f[0], wv, acc[2]); acc[3] = fmaf(f[1], wv, acc[3]);
        f = __builtin_amdgcn_cvt_pk_f32_fp8((int)v.y, false);
        acc[4] = fmaf(f[0], wv, acc[4]); acc[5] = fmaf(f[1], wv, acc[5]);
        f = __builtin_amdgcn_cvt_pk_f32_fp8((int)v.y, true);
        acc[6] = fmaf(f[0], wv, acc[6]); acc[7] = fmaf(f[1], wv, acc[7]);
    }

#pragma unroll
    for (int o = 16; o <= 32; o <<= 1)
#pragma unroll
        for (int i = 0; i < 8; i++) acc[i] += __shfl_xor(acc[i], o);

    if (lane < 16) {
        float r[8];
#pragma unroll
        for (int i = 0; i < 8; i++) r[i] = fmaxf(acc[i] + b1[q * 8 + i], 0.f);
        __half2 p0 = __floats2half2_rn(r[0], r[1]);
        __half2 p1 = __floats2half2_rn(r[2], r[3]);
        __half2 p2 = __floats2half2_rn(r[4], r[5]);
        __half2 p3 = __floats2half2_rn(r[6], r[7]);
        uint4 o4;
        o4.x = *(unsigned*)&p0; o4.y = *(unsigned*)&p1;
        o4.z = *(unsigned*)&p2; o4.w = *(unsigned*)&p3;
        *(uint4*)(H2 + (size_t)node * HID + q * 8) = o4;
    }
}

// ---------------- GEMM2 (MFMA fp16, no LDS): Z8 = fp8(H2 @ W2), 64 B rows ----------------

__global__ __launch_bounds__(256) void k_gemm2(const __half* __restrict__ H2,
                                               const __half* __restrict__ W2t,
                                               unsigned char* __restrict__ Z8, int M) {
    int tid = threadIdx.x;
    int wid = tid >> 6, lane = tid & 63;
    int q = lane & 15, kg = lane >> 4;
    int row = blockIdx.x * 64 + wid * 16 + q;
    int lrow = min(row, M - 1);
    const __half* hr = H2 + (size_t)lrow * HID;

    half8_t a[4];
#pragma unroll
    for (int kt = 0; kt < 4; kt++) a[kt] = *(const half8_t*)(hr + kt * 32 + kg * 8);

    f32x4 acc[3];
#pragma unroll
    for (int c = 0; c < 3; c++) acc[c] = (f32x4){0.f, 0.f, 0.f, 0.f};

#pragma unroll
    for (int c = 0; c < 3; c++) {
        const __half* wc = W2t + (size_t)(c * 16 + q) * HID + kg * 8;
#pragma unroll
        for (int kt = 0; kt < 4; kt++) {
            half8_t b = *(const half8_t*)(wc + kt * 32);
            acc[c] = __builtin_amdgcn_mfma_f32_16x16x32_f16(a[kt], b, acc[c], 0, 0, 0);
        }
    }

    int r0 = blockIdx.x * 64 + wid * 16 + kg * 4;
#pragma unroll
    for (int c = 0; c < 3; c++) {
        int col = c * 16 + q;
        if (col < NCLS) {
#pragma unroll
            for (int i = 0; i < 4; i++) {
                int r = r0 + i;
                if (r < M) {
                    int p = __builtin_amdgcn_cvt_pk_fp8_f32(acc[c][i], acc[c][i], 0, false);
                    Z8[(size_t)r * ZPB + col] = (unsigned char)(p & 0xff);
                }
            }
        }
    }
}

// ---------------- agg2 + bias + log_softmax (fp8 Z, 1 line/gather) ----------------
// one wave/node; 8x8-lane groups; group g strides edges g, g+8, ...; lanes q>=5
// read row padding into class-slots 40..63 which the softmax discards.

__global__ __launch_bounds__(256) void k_agg2(const unsigned char* __restrict__ Z8,
                                              const unsigned* __restrict__ eew,
                                              const int* __restrict__ off,
                                              const int* __restrict__ cnt,
                                              const float* __restrict__ dinv,
                                              const float* __restrict__ b2,
                                              float* __restrict__ Out, int n) {
    int node = blockIdx.x * 4 + (threadIdx.x >> 6);
    int lane = threadIdx.x & 63;
    if (node >= n) return;
    int q = lane & 7, g = lane >> 3;
    float di = dinv[node];
    int start = off[node], ne = cnt[node];

    float acc[8] = {0.f, 0.f, 0.f, 0.f, 0.f, 0.f, 0.f, 0.f};

    if (g == 0) {
        uint2 v = *(const uint2*)(Z8 + (size_t)node * ZPB + q * 8);
        float wv = di * di;
        f32x2 f;
        f = __builtin_amdgcn_cvt_pk_f32_fp8((int)v.x, false);
        acc[0] = f[0] * wv; acc[1] = f[1] * wv;
        f = __builtin_amdgcn_cvt_pk_f32_fp8((int)v.x, true);
        acc[2] = f[0] * wv; acc[3] = f[1] * wv;
        f = __builtin_amdgcn_cvt_pk_f32_fp8((int)v.y, false);
        acc[4] = f[0] * wv; acc[5] = f[1] * wv;
        f = __builtin_amdgcn_cvt_pk_f32_fp8((int)v.y, true);
        acc[6] = f[0] * wv; acc[7] = f[1] * wv;
    }

#pragma unroll 2
    for (int j = g; j < ne; j += 8) {
        unsigned u = __builtin_nontemporal_load(eew + start + j);
        int s = (int)(u >> 15);
        float wv = __uint_as_float((u & 0x7FFFu) << 17);
        uint2 v = *(const uint2*)(Z8 + (size_t)s * ZPB + q * 8);
        f32x2 f;
        f = __builtin_amdgcn_cvt_pk_f32_fp8((int)v.x, false);
        acc[0] = fmaf(f[0], wv, acc[0]); acc[1] = fmaf(f[1], wv, acc[1]);
        f = __builtin_amdgcn_cvt_pk_f32_fp8((int)v.x, true);
        acc[2] = fmaf(f[0], wv, acc[2]); acc[3] = fmaf(f[1], wv, acc[3]);
        f = __builtin_amdgcn_cvt_pk_f32_fp8((int)v.y, false);
        acc[4] = fmaf(f[0], wv, acc[4]); acc[5] = fmaf(f[1], wv, acc[5]);
        f = __builtin_amdgcn_cvt_pk_f32_fp8((int)v.y, true);
        acc[6] = fmaf(f[0], wv, acc[6]); acc[7] = fmaf(f[1], wv, acc[7]);
    }

#pragma unroll
    for (int o = 8; o <= 32; o <<= 1)
#pragma unroll
        for (int i = 0; i < 8; i++) acc[i] += __shfl_xor(acc[i], o);

    bool valid = (q < 5);
    float v[8];
    float m = -INFINITY;
#pragma unroll
    for (int i = 0; i < 8; i++) {
        v[i] = valid ? acc[i] + b2[q * 8 + i] : -INFINITY;
        m = fmaxf(m, v[i]);
    }
#pragma unroll
    for (int o = 1; o <= 4; o <<= 1) m = fmaxf(m, __shfl_xor(m, o));
    float ssum = 0.f;
#pragma unroll
    for (int i = 0; i < 8; i++)
        if (valid) ssum += __expf(v[i] - m);
#pragma unroll
    for (int o = 1; o <= 4; o <<= 1) ssum += __shfl_xor(ssum, o);
    float lse = m + logf(ssum);

    if (lane < 5) {
        float4 w0 = make_float4(v[0] - lse, v[1] - lse, v[2] - lse, v[3] - lse);
        float4 w1 = make_float4(v[4] - lse, v[5] - lse, v[6] - lse, v[7] - lse);
        float* op = Out + (size_t)node * NCLS + lane * 8;
        *(float4*)op = w0;
        *(float4*)(op + 4) = w1;
    }
}

// ---------------- launch ----------------

extern "C" void kernel_launch(void* const* d_in, const int* in_sizes, int n_in,
                              void* d_out, int out_size, void* d_ws, size_t ws_size,
                              hipStream_t stream) {
    const float* x  = (const float*)d_in[0];
    const int* ei   = (const int*)d_in[1];
    const float* W1 = (const float*)d_in[2];
    const float* b1 = (const float*)d_in[3];
    const float* W2 = (const float*)d_in[4];
    const float* b2 = (const float*)d_in[5];
    float* out = (float*)d_out;

    const int n = in_sizes[0] / FIN;   // 100000
    const int E = in_sizes[1] / 2;     // 1600000
    const int* src = ei;
    const int* dst = ei + E;
    const int nbk = (n + BKT_SZ - 1) >> BKT_SHIFT;  // 196

    char* w = (char*)d_ws;
    auto alloc = [&](size_t bytes) {
        char* p = w;
        w += (bytes + 255) & ~(size_t)255;
        return p;
    };
    int* cnt     = (int*)alloc((size_t)n * 4);
    int* off     = (int*)alloc((size_t)n * 4);
    int* bsum    = (int*)alloc(512);
    float* dinv  = (float*)alloc((size_t)n * 4);
    int* boff    = (int*)alloc((size_t)(nbk + 1) * 4);
    int* bcur    = (int*)alloc((size_t)nbk * 4);
    int2* ebkt   = (int2*)alloc((size_t)E * 8);
    unsigned* eew = (unsigned*)alloc((size_t)E * 4);
    ushort* wt   = (ushort*)alloc((size_t)FIN * HID * 2);
    __half* w2t  = (__half*)alloc((size_t)48 * HID * 2);
    unsigned char* H8 = (unsigned char*)alloc((size_t)n * HID);
    __half* H2   = (__half*)alloc((size_t)n * HID * 2);
    unsigned char* Z8 = (unsigned char*)alloc((size_t)n * ZPB);

    const int nb = (n + 1023) / 1024;

    k_w1_cvt<<<(FIN * HID) / 256, 256, 0, stream>>>(W1, wt);
    k_w2_cvt<<<(48 * HID) / 256, 256, 0, stream>>>(W2, w2t);

    // CSR: hist + node-level exclusive scan + dinv
    k_zero_int<<<(n + 255) / 256, 256, 0, stream>>>(cnt, n);
    k_hist<<<(E + 255) / 256, 256, 0, stream>>>(dst, E, cnt);
    k_scan1<<<nb, 1024, 0, stream>>>(cnt, off, bsum, n);
    k_scan2<<<1, 64, 0, stream>>>(bsum, nb);
    k_scan3<<<(n + 255) / 256, 256, 0, stream>>>(off, cnt, bsum, dinv, n);

    // two-phase bucket scatter (packs src+weight into 4 B/edge)
    k_binit<<<1, 256, 0, stream>>>(off, boff, bcur, n, E, nbk);
    k_bucketize<<<(E + CHUNK - 1) / CHUNK, 256, 0, stream>>>(src, dst, E, bcur, ebkt, nbk);
    k_sortbkt<<<nbk, 512, 0, stream>>>(ebkt, boff, off, dinv, eew, n);

    // layer 1
    k_gemm1<<<(n + 63) / 64, 256, 0, stream>>>(x, wt, H8, n);
    k_agg1<<<(n + 3) / 4, 256, 0, stream>>>(H8, eew, off, cnt, dinv, b1, H2, n);

    // layer 2 + log_softmax
    k_gemm2<<<(n + 63) / 64, 256, 0, stream>>>(H2, w2t, Z8, n);
    k_agg2<<<(n + 3) / 4, 256, 0, stream>>>(Z8, eew, off, cnt, dinv, b2, out, n);
}

// Round 10
// 282.898 us; speedup vs baseline: 1.0724x; 1.0724x over previous
//
#include <hip/hip_runtime.h>
#include <hip/hip_fp16.h>
#include <math.h>

#define FIN 256
#define HID 128
#define NCLS 40
#define ZPB 64   // fp8 Z row stride in bytes (one cache line)
#define BKT_SHIFT 9
#define BKT_SZ 512
#define CHUNK 2048

typedef __attribute__((ext_vector_type(8))) short short8_t;
typedef __attribute__((ext_vector_type(8))) _Float16 half8_t;
typedef __attribute__((ext_vector_type(4))) float f32x4;
typedef __attribute__((ext_vector_type(2))) float f32x2;

static __device__ __forceinline__ ushort f2bf(float f) {
    unsigned u = __float_as_uint(f);
    u += 0x7FFF + ((u >> 16) & 1);
    return (ushort)(u >> 16);
}

// packed edge: src (17 bits) << 15 | top-15-bits-of-fp32-weight (sign0+exp8+mant6)
static __device__ __forceinline__ unsigned pack_ew(int s, float w) {
    return ((unsigned)s << 15) | (__float_as_uint(w) >> 17);
}

// ---------------- prep: zero cnt + convert W1 (bf16^T) + W2 (f16^T padded) ----------------

__global__ void k_prep(int* __restrict__ cnt, const float* __restrict__ W1,
                       ushort* __restrict__ Wt, const float* __restrict__ W2,
                       __half* __restrict__ W2t, int n) {
    int i = blockIdx.x * 256 + threadIdx.x;
    if (i < n) cnt[i] = 0;
    if (i < FIN * HID) {
        int c = i >> 8, k = i & 255;
        Wt[i] = f2bf(W1[(size_t)k * HID + c]);
    }
    if (i < 48 * HID) {
        int c = i >> 7, k = i & 127;
        W2t[i] = __float2half((c < NCLS) ? W2[(size_t)k * NCLS + c] : 0.f);
    }
}

// ---------------- CSR build: hist + node-level scan ----------------

__global__ void k_hist(const int* __restrict__ dst, int E, int* __restrict__ cnt) {
    int e = blockIdx.x * blockDim.x + threadIdx.x;
    if (e < E) atomicAdd(&cnt[dst[e]], 1);
}

__global__ __launch_bounds__(1024) void k_scan1(const int* __restrict__ cnt, int* __restrict__ off,
                                                int* __restrict__ bsum, int n) {
    __shared__ int sm[1024];
    int t = threadIdx.x;
    int i = blockIdx.x * 1024 + t;
    int v = (i < n) ? cnt[i] : 0;
    sm[t] = v;
    __syncthreads();
    for (int o = 1; o < 1024; o <<= 1) {
        int u = (t >= o) ? sm[t - o] : 0;
        __syncthreads();
        sm[t] += u;
        __syncthreads();
    }
    if (i < n) off[i] = sm[t];
    if (t == 1023) bsum[blockIdx.x] = sm[1023];
}

__global__ void k_scan2(int* __restrict__ bsum, int nb) {
    int lane = threadIdx.x;
    int v0 = (lane < nb) ? bsum[lane] : 0;
    int v1 = (64 + lane < nb) ? bsum[64 + lane] : 0;
    int o0 = v0, o1 = v1;
    for (int o = 1; o < 64; o <<= 1) {
        int t = __shfl_up(v0, o);
        if (lane >= o) v0 += t;
    }
    int tot0 = __shfl(v0, 63);
    for (int o = 1; o < 64; o <<= 1) {
        int t = __shfl_up(v1, o);
        if (lane >= o) v1 += t;
    }
    v1 += tot0;
    if (lane < nb) bsum[lane] = v0 - o0;
    if (64 + lane < nb) bsum[64 + lane] = v1 - o1;
}

__global__ void k_scan3(int* __restrict__ off, const int* __restrict__ cnt,
                        const int* __restrict__ bsum, float* __restrict__ dinv, int n) {
    int i = blockIdx.x * blockDim.x + threadIdx.x;
    if (i < n) {
        int excl = off[i] - cnt[i] + bsum[i >> 10];
        off[i] = excl;
        dinv[i] = rsqrtf((float)(cnt[i] + 1));
    }
}

__global__ void k_binit(const int* __restrict__ off, int* __restrict__ boff,
                        int* __restrict__ bcur, int n, int E, int nbk) {
    int t = threadIdx.x;
    if (t <= nbk) {
        int idx = t << BKT_SHIFT;
        int v = (idx >= n) ? E : off[idx];
        boff[t] = v;
        if (t < nbk) bcur[t] = v;
    }
}

// ---------------- phase 1: bucketize edges by dst>>9 ----------------

__global__ __launch_bounds__(256) void k_bucketize(const int* __restrict__ src,
                                                   const int* __restrict__ dst, int E,
                                                   int* __restrict__ bcur,
                                                   int2* __restrict__ ebkt, int nbk) {
    __shared__ int hist[256];
    __shared__ int scanb[256];
    __shared__ int base[256];
    __shared__ int gbase[256];
    __shared__ int2 stage[CHUNK];
    int t = threadIdx.x;
    int e0 = blockIdx.x * CHUNK;
    int cntc = min(CHUNK, E - e0);
    hist[t] = 0;
    __syncthreads();

    int s_[8], d_[8], bk_[8], rk_[8];
#pragma unroll
    for (int i = 0; i < 8; i++) {
        int j = t + i * 256;
        if (j < cntc) {
            int s = src[e0 + j], d = dst[e0 + j];
            s_[i] = s; d_[i] = d;
            bk_[i] = d >> BKT_SHIFT;
            rk_[i] = atomicAdd(&hist[bk_[i]], 1);
        } else {
            bk_[i] = -1;
        }
    }
    __syncthreads();

    scanb[t] = hist[t];
    __syncthreads();
    for (int o = 1; o < 256; o <<= 1) {
        int u = (t >= o) ? scanb[t - o] : 0;
        __syncthreads();
        scanb[t] += u;
        __syncthreads();
    }
    base[t] = scanb[t] - hist[t];
    if (t < nbk && hist[t] > 0) gbase[t] = atomicAdd(&bcur[t], hist[t]);
    __syncthreads();

#pragma unroll
    for (int i = 0; i < 8; i++) {
        if (bk_[i] >= 0) stage[base[bk_[i]] + rk_[i]] = make_int2(s_[i], d_[i]);
    }
    __syncthreads();

#pragma unroll
    for (int i = 0; i < 8; i++) {
        int j = t + i * 256;
        if (j < cntc) {
            int2 e = stage[j];
            int bk = e.y >> BKT_SHIFT;
            ebkt[gbase[bk] + (j - base[bk])] = e;
        }
    }
}

// ---------------- phase 2: within-bucket placement; pack (src, weight) ----------------

__global__ __launch_bounds__(512) void k_sortbkt(const int2* __restrict__ ebkt,
                                                 const int* __restrict__ boff,
                                                 const int* __restrict__ off,
                                                 const float* __restrict__ dinv,
                                                 unsigned* __restrict__ eew, int n) {
    __shared__ int cur[BKT_SZ];
    __shared__ float ldin[BKT_SZ];
    int b = blockIdx.x, t = threadIdx.x;
    int n0 = b << BKT_SHIFT;
    int nn = min(BKT_SZ, n - n0);
    for (int i = t; i < nn; i += 512) {
        cur[i] = off[n0 + i];
        ldin[i] = dinv[n0 + i];
    }
    __syncthreads();
    int e0 = boff[b], e1 = boff[b + 1];
    for (int e = e0 + t; e < e1; e += 512) {
        int2 ed = ebkt[e];
        int s = ed.x, dl = ed.y - n0;
        float w = dinv[s] * ldin[dl];
        int pos = atomicAdd(&cur[dl], 1);
        eew[pos] = pack_ew(s, w);
    }
}

// ---------------- GEMM1 (MFMA bf16): H8 = fp8(X @ W1), x prefetched ----------------

__global__ __launch_bounds__(256) void k_gemm1(const float* __restrict__ X,
                                               const ushort* __restrict__ Wt,
                                               unsigned char* __restrict__ H8, int M) {
    __shared__ uint4 wlds[128 * 32];  // 64 KB; reused as f32 staging in epilogue
    int tid = threadIdx.x;
    const uint4* wg = (const uint4*)Wt;
#pragma unroll
    for (int i = 0; i < 16; i++) {
        int e = tid + i * 256;
        int r = e >> 5, ch = e & 31;
        wlds[r * 32 + (ch ^ (r & 7))] = wg[e];
    }

    int wid = tid >> 6, lane = tid & 63;
    int q = lane & 15, kg = lane >> 4;
    int grow_in = blockIdx.x * 64 + wid * 16 + q;
    int lrow = min(grow_in, M - 1);
    const float* xr = X + (size_t)lrow * FIN;

    // prefetch all 8 K-tiles (16 independent dwordx4 loads)
    float4 xf0[8], xf1[8];
#pragma unroll
    for (int kt = 0; kt < 8; kt++) {
        int k0 = kt * 32 + kg * 8;
        xf0[kt] = *(const float4*)(xr + k0);
        xf1[kt] = *(const float4*)(xr + k0 + 4);
    }
    __syncthreads();

    f32x4 acc[8];
#pragma unroll
    for (int c = 0; c < 8; c++) acc[c] = (f32x4){0.f, 0.f, 0.f, 0.f};

#pragma unroll
    for (int kt = 0; kt < 8; kt++) {
        unsigned r0, r1, r2, r3;
        asm("v_cvt_pk_bf16_f32 %0, %1, %2" : "=v"(r0) : "v"(xf0[kt].x), "v"(xf0[kt].y));
        asm("v_cvt_pk_bf16_f32 %0, %1, %2" : "=v"(r1) : "v"(xf0[kt].z), "v"(xf0[kt].w));
        asm("v_cvt_pk_bf16_f32 %0, %1, %2" : "=v"(r2) : "v"(xf1[kt].x), "v"(xf1[kt].y));
        asm("v_cvt_pk_bf16_f32 %0, %1, %2" : "=v"(r3) : "v"(xf1[kt].z), "v"(xf1[kt].w));
        union { uint4 u; short8_t s; } cv;
        cv.u = make_uint4(r0, r1, r2, r3);
        short8_t a = cv.s;
        int ch = kt * 4 + kg;
#pragma unroll
        for (int c = 0; c < 8; c++) {
            int col = c * 16 + q;
            short8_t b = *(const short8_t*)&wlds[col * 32 + (ch ^ (col & 7))];
            acc[c] = __builtin_amdgcn_mfma_f32_16x16x32_bf16(a, b, acc[c], 0, 0, 0);
        }
    }

    __syncthreads();
    float* st = (float*)wlds;  // [64][132]
#pragma unroll
    for (int c = 0; c < 8; c++) {
        int col = c * 16 + q;
#pragma unroll
        for (int i = 0; i < 4; i++) {
            int lr = wid * 16 + kg * 4 + i;
            st[lr * 132 + col] = acc[c][i];
        }
    }
    __syncthreads();
    int orow = tid >> 2, seg = tid & 3;
    int grow = blockIdx.x * 64 + orow;
    if (grow < M) {
        const float* sp = st + orow * 132 + seg * 32;
        unsigned u[8];
#pragma unroll
        for (int k = 0; k < 8; k++) {
            int p = 0;
            p = __builtin_amdgcn_cvt_pk_fp8_f32(sp[4 * k + 0], sp[4 * k + 1], p, false);
            p = __builtin_amdgcn_cvt_pk_fp8_f32(sp[4 * k + 2], sp[4 * k + 3], p, true);
            u[k] = (unsigned)p;
        }
        uint4* op = (uint4*)(H8 + (size_t)grow * HID + seg * 32);
        op[0] = make_uint4(u[0], u[1], u[2], u[3]);
        op[1] = make_uint4(u[4], u[5], u[6], u[7]);
    }
}

// ---------------- agg1: H2 = fp16(relu(b1 + sum w*H8[s])) ----------------
// one wave/node; 4x16-lane groups; batched packed-edge prefetch + shfl distribution (r8)

__global__ __launch_bounds__(256) void k_agg1(const unsigned char* __restrict__ H8,
                                              const unsigned* __restrict__ eew,
                                              const int* __restrict__ off,
                                              const int* __restrict__ cnt,
                                              const float* __restrict__ dinv,
                                              const float* __restrict__ b1,
                                              __half* __restrict__ H2, int n) {
    int node = blockIdx.x * 4 + (threadIdx.x >> 6);
    int lane = threadIdx.x & 63;
    if (node >= n) return;
    int q = lane & 15, g = lane >> 4;
    float di = dinv[node];
    int start = off[node], ne = cnt[node];

    float acc[8] = {0.f, 0.f, 0.f, 0.f, 0.f, 0.f, 0.f, 0.f};

    // self-loop (group 0 only)
    if (g == 0) {
        uint2 v = *(const uint2*)(H8 + (size_t)node * HID + q * 8);
        float wv = di * di;
        f32x2 f;
        f = __builtin_amdgcn_cvt_pk_f32_fp8((int)v.x, false);
        acc[0] = f[0] * wv; acc[1] = f[1] * wv;
        f = __builtin_amdgcn_cvt_pk_f32_fp8((int)v.x, true);
        acc[2] = f[0] * wv; acc[3] = f[1] * wv;
        f = __builtin_amdgcn_cvt_pk_f32_fp8((int)v.y, false);
        acc[4] = f[0] * wv; acc[5] = f[1] * wv;
        f = __builtin_amdgcn_cvt_pk_f32_fp8((int)v.y, true);
        acc[6] = f[0] * wv; acc[7] = f[1] * wv;
    }

    for (int b0 = 0; b0 < ne; b0 += 64) {
        int nb = min(64, ne - b0);
        unsigned u_l = 0;
        if (lane < nb) u_l = eew[start + b0 + lane];
        for (int jj = 0; jj < nb; jj += 4) {
            unsigned u = __shfl(u_l, jj + g);
            int s = (int)(u >> 15);
            float wv = __uint_as_float((u & 0x7FFFu) << 17);  // 0 for tail lanes
            uint2 v = *(const uint2*)(H8 + (size_t)s * HID + q * 8);
            f32x2 f;
            f = __builtin_amdgcn_cvt_pk_f32_fp8((int)v.x, false);
            acc[0] = fmaf(f[0], wv, acc[0]); acc[1] = fmaf(f[1], wv, acc[1]);
            f = __builtin_amdgcn_cvt_pk_f32_fp8((int)v.x, true);
            acc[2] = fmaf(f[0], wv, acc[2]); acc[3] = fmaf(f[1], wv, acc[3]);
            f = __builtin_amdgcn_cvt_pk_f32_fp8((int)v.y, false);
            acc[4] = fmaf(f[0], wv, acc[4]); acc[5] = fmaf(f[1], wv, acc[5]);
            f = __builtin_amdgcn_cvt_pk_f32_fp8((int)v.y, true);
            acc[6] = fmaf(f[0], wv, acc[6]); acc[7] = fmaf(f[1], wv, acc[7]);
        }
    }

#pragma unroll
    for (int o = 16; o <= 32; o <<= 1)
#pragma unroll
        for (int i = 0; i < 8; i++) acc[i] += __shfl_xor(acc[i], o);

    if (lane < 16) {
        float r[8];
#pragma unroll
        for (int i = 0; i < 8; i++) r[i] = fmaxf(acc[i] + b1[q * 8 + i], 0.f);
        __half2 p0 = __floats2half2_rn(r[0], r[1]);
        __half2 p1 = __floats2half2_rn(r[2], r[3]);
        __half2 p2 = __floats2half2_rn(r[4], r[5]);
        __half2 p3 = __floats2half2_rn(r[6], r[7]);
        uint4 o4;
        o4.x = *(unsigned*)&p0; o4.y = *(unsigned*)&p1;
        o4.z = *(unsigned*)&p2; o4.w = *(unsigned*)&p3;
        *(uint4*)(H2 + (size_t)node * HID + q * 8) = o4;
    }
}

// ---------------- GEMM2 (MFMA fp16, no LDS): Z8 = fp8(H2 @ W2), 64 B rows ----------------

__global__ __launch_bounds__(256) void k_gemm2(const __half* __restrict__ H2,
                                               const __half* __restrict__ W2t,
                                               unsigned char* __restrict__ Z8, int M) {
    int tid = threadIdx.x;
    int wid = tid >> 6, lane = tid & 63;
    int q = lane & 15, kg = lane >> 4;
    int row = blockIdx.x * 64 + wid * 16 + q;
    int lrow = min(row, M - 1);
    const __half* hr = H2 + (size_t)lrow * HID;

    half8_t a[4];
#pragma unroll
    for (int kt = 0; kt < 4; kt++) a[kt] = *(const half8_t*)(hr + kt * 32 + kg * 8);

    f32x4 acc[3];
#pragma unroll
    for (int c = 0; c < 3; c++) acc[c] = (f32x4){0.f, 0.f, 0.f, 0.f};

#pragma unroll
    for (int c = 0; c < 3; c++) {
        const __half* wc = W2t + (size_t)(c * 16 + q) * HID + kg * 8;
#pragma unroll
        for (int kt = 0; kt < 4; kt++) {
            half8_t b = *(const half8_t*)(wc + kt * 32);
            acc[c] = __builtin_amdgcn_mfma_f32_16x16x32_f16(a[kt], b, acc[c], 0, 0, 0);
        }
    }

    int r0 = blockIdx.x * 64 + wid * 16 + kg * 4;
#pragma unroll
    for (int c = 0; c < 3; c++) {
        int col = c * 16 + q;
        if (col < NCLS) {
#pragma unroll
            for (int i = 0; i < 4; i++) {
                int r = r0 + i;
                if (r < M) {
                    int p = __builtin_amdgcn_cvt_pk_fp8_f32(acc[c][i], acc[c][i], 0, false);
                    Z8[(size_t)r * ZPB + col] = (unsigned char)(p & 0xff);
                }
            }
        }
    }
}

// ---------------- agg2 + bias + log_softmax (fp8 Z, 1 line/gather) ----------------
// one wave/node; 8x8-lane groups; batched packed-edge prefetch + shfl distribution;
// lanes q>=5 read row padding into class-slots 40..63 which the softmax discards.

__global__ __launch_bounds__(256) void k_agg2(const unsigned char* __restrict__ Z8,
                                              const unsigned* __restrict__ eew,
                                              const int* __restrict__ off,
                                              const int* __restrict__ cnt,
                                              const float* __restrict__ dinv,
                                              const float* __restrict__ b2,
                                              float* __restrict__ Out, int n) {
    int node = blockIdx.x * 4 + (threadIdx.x >> 6);
    int lane = threadIdx.x & 63;
    if (node >= n) return;
    int q = lane & 7, g = lane >> 3;
    float di = dinv[node];
    int start = off[node], ne = cnt[node];

    float acc[8] = {0.f, 0.f, 0.f, 0.f, 0.f, 0.f, 0.f, 0.f};

    if (g == 0) {
        uint2 v = *(const uint2*)(Z8 + (size_t)node * ZPB + q * 8);
        float wv = di * di;
        f32x2 f;
        f = __builtin_amdgcn_cvt_pk_f32_fp8((int)v.x, false);
        acc[0] = f[0] * wv; acc[1] = f[1] * wv;
        f = __builtin_amdgcn_cvt_pk_f32_fp8((int)v.x, true);
        acc[2] = f[0] * wv; acc[3] = f[1] * wv;
        f = __builtin_amdgcn_cvt_pk_f32_fp8((int)v.y, false);
        acc[4] = f[0] * wv; acc[5] = f[1] * wv;
        f = __builtin_amdgcn_cvt_pk_f32_fp8((int)v.y, true);
        acc[6] = f[0] * wv; acc[7] = f[1] * wv;
    }

    for (int b0 = 0; b0 < ne; b0 += 64) {
        int nb = min(64, ne - b0);
        unsigned u_l = 0;
        if (lane < nb) u_l = eew[start + b0 + lane];
        for (int jj = 0; jj < nb; jj += 8) {
            unsigned u = __shfl(u_l, jj + g);
            int s = (int)(u >> 15);
            float wv = __uint_as_float((u & 0x7FFFu) << 17);  // 0 for tail lanes
            uint2 v = *(const uint2*)(Z8 + (size_t)s * ZPB + q * 8);
            f32x2 f;
            f = __builtin_amdgcn_cvt_pk_f32_fp8((int)v.x, false);
            acc[0] = fmaf(f[0], wv, acc[0]); acc[1] = fmaf(f[1], wv, acc[1]);
            f = __builtin_amdgcn_cvt_pk_f32_fp8((int)v.x, true);
            acc[2] = fmaf(f[0], wv, acc[2]); acc[3] = fmaf(f[1], wv, acc[3]);
            f = __builtin_amdgcn_cvt_pk_f32_fp8((int)v.y, false);
            acc[4] = fmaf(f[0], wv, acc[4]); acc[5] = fmaf(f[1], wv, acc[5]);
            f = __builtin_amdgcn_cvt_pk_f32_fp8((int)v.y, true);
            acc[6] = fmaf(f[0], wv, acc[6]); acc[7] = fmaf(f[1], wv, acc[7]);
        }
    }

#pragma unroll
    for (int o = 8; o <= 32; o <<= 1)
#pragma unroll
        for (int i = 0; i < 8; i++) acc[i] += __shfl_xor(acc[i], o);

    bool valid = (q < 5);
    float v[8];
    float m = -INFINITY;
#pragma unroll
    for (int i = 0; i < 8; i++) {
        v[i] = valid ? acc[i] + b2[q * 8 + i] : -INFINITY;
        m = fmaxf(m, v[i]);
    }
#pragma unroll
    for (int o = 1; o <= 4; o <<= 1) m = fmaxf(m, __shfl_xor(m, o));
    float ssum = 0.f;
#pragma unroll
    for (int i = 0; i < 8; i++)
        if (valid) ssum += __expf(v[i] - m);
#pragma unroll
    for (int o = 1; o <= 4; o <<= 1) ssum += __shfl_xor(ssum, o);
    float lse = m + logf(ssum);

    if (lane < 5) {
        float4 w0 = make_float4(v[0] - lse, v[1] - lse, v[2] - lse, v[3] - lse);
        float4 w1 = make_float4(v[4] - lse, v[5] - lse, v[6] - lse, v[7] - lse);
        float* op = Out + (size_t)node * NCLS + lane * 8;
        *(float4*)op = w0;
        *(float4*)(op + 4) = w1;
    }
}

// ---------------- launch ----------------

extern "C" void kernel_launch(void* const* d_in, const int* in_sizes, int n_in,
                              void* d_out, int out_size, void* d_ws, size_t ws_size,
                              hipStream_t stream) {
    const float* x  = (const float*)d_in[0];
    const int* ei   = (const int*)d_in[1];
    const float* W1 = (const float*)d_in[2];
    const float* b1 = (const float*)d_in[3];
    const float* W2 = (const float*)d_in[4];
    const float* b2 = (const float*)d_in[5];
    float* out = (float*)d_out;

    const int n = in_sizes[0] / FIN;   // 100000
    const int E = in_sizes[1] / 2;     // 1600000
    const int* src = ei;
    const int* dst = ei + E;
    const int nbk = (n + BKT_SZ - 1) >> BKT_SHIFT;  // 196

    char* w = (char*)d_ws;
    auto alloc = [&](size_t bytes) {
        char* p = w;
        w += (bytes + 255) & ~(size_t)255;
        return p;
    };
    int* cnt     = (int*)alloc((size_t)n * 4);
    int* off     = (int*)alloc((size_t)n * 4);
    int* bsum    = (int*)alloc(512);
    float* dinv  = (float*)alloc((size_t)n * 4);
    int* boff    = (int*)alloc((size_t)(nbk + 1) * 4);
    int* bcur    = (int*)alloc((size_t)nbk * 4);
    int2* ebkt   = (int2*)alloc((size_t)E * 8);
    unsigned* eew = (unsigned*)alloc((size_t)E * 4);
    ushort* wt   = (ushort*)alloc((size_t)FIN * HID * 2);
    __half* w2t  = (__half*)alloc((size_t)48 * HID * 2);
    unsigned char* H8 = (unsigned char*)alloc((size_t)n * HID);
    __half* H2   = (__half*)alloc((size_t)n * HID * 2);
    unsigned char* Z8 = (unsigned char*)alloc((size_t)n * ZPB);

    const int nb = (n + 1023) / 1024;

    // prep: zero cnt + convert both weight matrices (one kernel)
    k_prep<<<(n + 255) / 256, 256, 0, stream>>>(cnt, W1, wt, W2, w2t, n);

    // CSR: hist + node-level exclusive scan + dinv
    k_hist<<<(E + 255) / 256, 256, 0, stream>>>(dst, E, cnt);
    k_scan1<<<nb, 1024, 0, stream>>>(cnt, off, bsum, n);
    k_scan2<<<1, 64, 0, stream>>>(bsum, nb);
    k_scan3<<<(n + 255) / 256, 256, 0, stream>>>(off, cnt, bsum, dinv, n);

    // two-phase bucket scatter (packs src+weight into 4 B/edge)
    k_binit<<<1, 256, 0, stream>>>(off, boff, bcur, n, E, nbk);
    k_bucketize<<<(E + CHUNK - 1) / CHUNK, 256, 0, stream>>>(src, dst, E, bcur, ebkt, nbk);
    k_sortbkt<<<nbk, 512, 0, stream>>>(ebkt, boff, off, dinv, eew, n);

    // layer 1
    k_gemm1<<<(n + 63) / 64, 256, 0, stream>>>(x, wt, H8, n);
    k_agg1<<<(n + 3) / 4, 256, 0, stream>>>(H8, eew, off, cnt, dinv, b1, H2, n);

    // layer 2 + log_softmax
    k_gemm2<<<(n + 63) / 64, 256, 0, stream>>>(H2, w2t, Z8, n);
    k_agg2<<<(n + 3) / 4, 256, 0, stream>>>(Z8, eew, off, cnt, dinv, b2, out, n);
}

// Round 11
// 237.662 us; speedup vs baseline: 1.2765x; 1.1903x over previous
//
#include <hip/hip_runtime.h>
#include <hip/hip_fp16.h>
#include <math.h>

#define FIN 256
#define HID 128
#define NCLS 40
#define ZPB 64   // fp8 Z row stride in bytes (one cache line)
#define BKT_SHIFT 9
#define BKT_SZ 512
#define CHUNK 2048

typedef __attribute__((ext_vector_type(8))) short short8_t;
typedef __attribute__((ext_vector_type(8))) _Float16 half8_t;
typedef __attribute__((ext_vector_type(4))) float f32x4;
typedef __attribute__((ext_vector_type(2))) float f32x2;

static __device__ __forceinline__ ushort f2bf(float f) {
    unsigned u = __float_as_uint(f);
    u += 0x7FFF + ((u >> 16) & 1);
    return (ushort)(u >> 16);
}

// packed edge: src (17 bits) << 15 | top-15-bits-of-fp32-weight (sign0+exp8+mant6)
static __device__ __forceinline__ unsigned pack_ew(int s, float w) {
    return ((unsigned)s << 15) | (__float_as_uint(w) >> 17);
}

// ---------------- prep: zero cnt + convert W1 (bf16^T) + W2 (f16^T padded) ----------------

__global__ void k_prep(int* __restrict__ cnt, const float* __restrict__ W1,
                       ushort* __restrict__ Wt, const float* __restrict__ W2,
                       __half* __restrict__ W2t, int n) {
    int i = blockIdx.x * 256 + threadIdx.x;
    if (i < n) cnt[i] = 0;
    if (i < FIN * HID) {
        int c = i >> 8, k = i & 255;
        Wt[i] = f2bf(W1[(size_t)k * HID + c]);
    }
    if (i < 48 * HID) {
        int c = i >> 7, k = i & 127;
        W2t[i] = __float2half((c < NCLS) ? W2[(size_t)k * NCLS + c] : 0.f);
    }
}

// ---------------- CSR build: hist + node-level scan ----------------

__global__ void k_hist(const int* __restrict__ dst, int E, int* __restrict__ cnt) {
    int e = blockIdx.x * blockDim.x + threadIdx.x;
    if (e < E) atomicAdd(&cnt[dst[e]], 1);
}

__global__ __launch_bounds__(1024) void k_scan1(const int* __restrict__ cnt, int* __restrict__ off,
                                                int* __restrict__ bsum, int n) {
    __shared__ int sm[1024];
    int t = threadIdx.x;
    int i = blockIdx.x * 1024 + t;
    int v = (i < n) ? cnt[i] : 0;
    sm[t] = v;
    __syncthreads();
    for (int o = 1; o < 1024; o <<= 1) {
        int u = (t >= o) ? sm[t - o] : 0;
        __syncthreads();
        sm[t] += u;
        __syncthreads();
    }
    if (i < n) off[i] = sm[t];
    if (t == 1023) bsum[blockIdx.x] = sm[1023];
}

__global__ void k_scan2(int* __restrict__ bsum, int nb) {
    int lane = threadIdx.x;
    int v0 = (lane < nb) ? bsum[lane] : 0;
    int v1 = (64 + lane < nb) ? bsum[64 + lane] : 0;
    int o0 = v0, o1 = v1;
    for (int o = 1; o < 64; o <<= 1) {
        int t = __shfl_up(v0, o);
        if (lane >= o) v0 += t;
    }
    int tot0 = __shfl(v0, 63);
    for (int o = 1; o < 64; o <<= 1) {
        int t = __shfl_up(v1, o);
        if (lane >= o) v1 += t;
    }
    v1 += tot0;
    if (lane < nb) bsum[lane] = v0 - o0;
    if (64 + lane < nb) bsum[64 + lane] = v1 - o1;
}

__global__ void k_scan3(int* __restrict__ off, const int* __restrict__ cnt,
                        const int* __restrict__ bsum, float* __restrict__ dinv, int n) {
    int i = blockIdx.x * blockDim.x + threadIdx.x;
    if (i < n) {
        int excl = off[i] - cnt[i] + bsum[i >> 10];
        off[i] = excl;
        dinv[i] = rsqrtf((float)(cnt[i] + 1));
    }
}

__global__ void k_binit(const int* __restrict__ off, int* __restrict__ boff,
                        int* __restrict__ bcur, int n, int E, int nbk) {
    int t = threadIdx.x;
    if (t <= nbk) {
        int idx = t << BKT_SHIFT;
        int v = (idx >= n) ? E : off[idx];
        boff[t] = v;
        if (t < nbk) bcur[t] = v;
    }
}

// ---------------- phase 1: bucketize edges by dst>>9 ----------------

__global__ __launch_bounds__(256) void k_bucketize(const int* __restrict__ src,
                                                   const int* __restrict__ dst, int E,
                                                   int* __restrict__ bcur,
                                                   int2* __restrict__ ebkt, int nbk) {
    __shared__ int hist[256];
    __shared__ int scanb[256];
    __shared__ int base[256];
    __shared__ int gbase[256];
    __shared__ int2 stage[CHUNK];
    int t = threadIdx.x;
    int e0 = blockIdx.x * CHUNK;
    int cntc = min(CHUNK, E - e0);
    hist[t] = 0;
    __syncthreads();

    int s_[8], d_[8], bk_[8], rk_[8];
#pragma unroll
    for (int i = 0; i < 8; i++) {
        int j = t + i * 256;
        if (j < cntc) {
            int s = src[e0 + j], d = dst[e0 + j];
            s_[i] = s; d_[i] = d;
            bk_[i] = d >> BKT_SHIFT;
            rk_[i] = atomicAdd(&hist[bk_[i]], 1);
        } else {
            bk_[i] = -1;
        }
    }
    __syncthreads();

    scanb[t] = hist[t];
    __syncthreads();
    for (int o = 1; o < 256; o <<= 1) {
        int u = (t >= o) ? scanb[t - o] : 0;
        __syncthreads();
        scanb[t] += u;
        __syncthreads();
    }
    base[t] = scanb[t] - hist[t];
    if (t < nbk && hist[t] > 0) gbase[t] = atomicAdd(&bcur[t], hist[t]);
    __syncthreads();

#pragma unroll
    for (int i = 0; i < 8; i++) {
        if (bk_[i] >= 0) stage[base[bk_[i]] + rk_[i]] = make_int2(s_[i], d_[i]);
    }
    __syncthreads();

#pragma unroll
    for (int i = 0; i < 8; i++) {
        int j = t + i * 256;
        if (j < cntc) {
            int2 e = stage[j];
            int bk = e.y >> BKT_SHIFT;
            ebkt[gbase[bk] + (j - base[bk])] = e;
        }
    }
}

// ---------------- phase 2: within-bucket placement; pack (src, weight) ----------------

__global__ __launch_bounds__(512) void k_sortbkt(const int2* __restrict__ ebkt,
                                                 const int* __restrict__ boff,
                                                 const int* __restrict__ off,
                                                 const float* __restrict__ dinv,
                                                 unsigned* __restrict__ eew, int n) {
    __shared__ int cur[BKT_SZ];
    __shared__ float ldin[BKT_SZ];
    int b = blockIdx.x, t = threadIdx.x;
    int n0 = b << BKT_SHIFT;
    int nn = min(BKT_SZ, n - n0);
    for (int i = t; i < nn; i += 512) {
        cur[i] = off[n0 + i];
        ldin[i] = dinv[n0 + i];
    }
    __syncthreads();
    int e0 = boff[b], e1 = boff[b + 1];
    for (int e = e0 + t; e < e1; e += 512) {
        int2 ed = ebkt[e];
        int s = ed.x, dl = ed.y - n0;
        float w = dinv[s] * ldin[dl];
        int pos = atomicAdd(&cur[dl], 1);
        eew[pos] = pack_ew(s, w);
    }
}

// ---------------- GEMM1 (MFMA bf16): H8 = fp8(X @ W1), x prefetched ----------------

__global__ __launch_bounds__(256) void k_gemm1(const float* __restrict__ X,
                                               const ushort* __restrict__ Wt,
                                               unsigned char* __restrict__ H8, int M) {
    __shared__ uint4 wlds[128 * 32];  // 64 KB; reused as f32 staging in epilogue
    int tid = threadIdx.x;
    const uint4* wg = (const uint4*)Wt;
#pragma unroll
    for (int i = 0; i < 16; i++) {
        int e = tid + i * 256;
        int r = e >> 5, ch = e & 31;
        wlds[r * 32 + (ch ^ (r & 7))] = wg[e];
    }

    int wid = tid >> 6, lane = tid & 63;
    int q = lane & 15, kg = lane >> 4;
    int grow_in = blockIdx.x * 64 + wid * 16 + q;
    int lrow = min(grow_in, M - 1);
    const float* xr = X + (size_t)lrow * FIN;

    float4 xf0[8], xf1[8];
#pragma unroll
    for (int kt = 0; kt < 8; kt++) {
        int k0 = kt * 32 + kg * 8;
        xf0[kt] = *(const float4*)(xr + k0);
        xf1[kt] = *(const float4*)(xr + k0 + 4);
    }
    __syncthreads();

    f32x4 acc[8];
#pragma unroll
    for (int c = 0; c < 8; c++) acc[c] = (f32x4){0.f, 0.f, 0.f, 0.f};

#pragma unroll
    for (int kt = 0; kt < 8; kt++) {
        unsigned r0, r1, r2, r3;
        asm("v_cvt_pk_bf16_f32 %0, %1, %2" : "=v"(r0) : "v"(xf0[kt].x), "v"(xf0[kt].y));
        asm("v_cvt_pk_bf16_f32 %0, %1, %2" : "=v"(r1) : "v"(xf0[kt].z), "v"(xf0[kt].w));
        asm("v_cvt_pk_bf16_f32 %0, %1, %2" : "=v"(r2) : "v"(xf1[kt].x), "v"(xf1[kt].y));
        asm("v_cvt_pk_bf16_f32 %0, %1, %2" : "=v"(r3) : "v"(xf1[kt].z), "v"(xf1[kt].w));
        union { uint4 u; short8_t s; } cv;
        cv.u = make_uint4(r0, r1, r2, r3);
        short8_t a = cv.s;
        int ch = kt * 4 + kg;
#pragma unroll
        for (int c = 0; c < 8; c++) {
            int col = c * 16 + q;
            short8_t b = *(const short8_t*)&wlds[col * 32 + (ch ^ (col & 7))];
            acc[c] = __builtin_amdgcn_mfma_f32_16x16x32_bf16(a, b, acc[c], 0, 0, 0);
        }
    }

    __syncthreads();
    float* st = (float*)wlds;  // [64][132]
#pragma unroll
    for (int c = 0; c < 8; c++) {
        int col = c * 16 + q;
#pragma unroll
        for (int i = 0; i < 4; i++) {
            int lr = wid * 16 + kg * 4 + i;
            st[lr * 132 + col] = acc[c][i];
        }
    }
    __syncthreads();
    int orow = tid >> 2, seg = tid & 3;
    int grow = blockIdx.x * 64 + orow;
    if (grow < M) {
        const float* sp = st + orow * 132 + seg * 32;
        unsigned u[8];
#pragma unroll
        for (int k = 0; k < 8; k++) {
            int p = 0;
            p = __builtin_amdgcn_cvt_pk_fp8_f32(sp[4 * k + 0], sp[4 * k + 1], p, false);
            p = __builtin_amdgcn_cvt_pk_fp8_f32(sp[4 * k + 2], sp[4 * k + 3], p, true);
            u[k] = (unsigned)p;
        }
        uint4* op = (uint4*)(H8 + (size_t)grow * HID + seg * 32);
        op[0] = make_uint4(u[0], u[1], u[2], u[3]);
        op[1] = make_uint4(u[4], u[5], u[6], u[7]);
    }
}

// ---------------- agg1: H2 = fp16(relu(b1 + sum w*H8[s])) ----------------
// one 16-lane group per node (16 nodes/block); no cross-group reduction

__global__ __launch_bounds__(256) void k_agg1(const unsigned char* __restrict__ H8,
                                              const unsigned* __restrict__ eew,
                                              const int* __restrict__ off,
                                              const int* __restrict__ cnt,
                                              const float* __restrict__ dinv,
                                              const float* __restrict__ b1,
                                              __half* __restrict__ H2, int n) {
    int tid = threadIdx.x;
    int node = blockIdx.x * 16 + (tid >> 4);
    int q = tid & 15;
    if (node >= n) return;
    float di = dinv[node];
    int start = off[node], ne = cnt[node];

    // self-loop
    float acc[8];
    {
        uint2 v = *(const uint2*)(H8 + (size_t)node * HID + q * 8);
        float wv = di * di;
        f32x2 f;
        f = __builtin_amdgcn_cvt_pk_f32_fp8((int)v.x, false);
        acc[0] = f[0] * wv; acc[1] = f[1] * wv;
        f = __builtin_amdgcn_cvt_pk_f32_fp8((int)v.x, true);
        acc[2] = f[0] * wv; acc[3] = f[1] * wv;
        f = __builtin_amdgcn_cvt_pk_f32_fp8((int)v.y, false);
        acc[4] = f[0] * wv; acc[5] = f[1] * wv;
        f = __builtin_amdgcn_cvt_pk_f32_fp8((int)v.y, true);
        acc[6] = f[0] * wv; acc[7] = f[1] * wv;
    }

#pragma unroll 2
    for (int j = 0; j < ne; ++j) {
        unsigned u = eew[start + j];          // group-uniform broadcast load
        int s = (int)(u >> 15);
        float wv = __uint_as_float((u & 0x7FFFu) << 17);
        uint2 v = *(const uint2*)(H8 + (size_t)s * HID + q * 8);
        f32x2 f;
        f = __builtin_amdgcn_cvt_pk_f32_fp8((int)v.x, false);
        acc[0] = fmaf(f[0], wv, acc[0]); acc[1] = fmaf(f[1], wv, acc[1]);
        f = __builtin_amdgcn_cvt_pk_f32_fp8((int)v.x, true);
        acc[2] = fmaf(f[0], wv, acc[2]); acc[3] = fmaf(f[1], wv, acc[3]);
        f = __builtin_amdgcn_cvt_pk_f32_fp8((int)v.y, false);
        acc[4] = fmaf(f[0], wv, acc[4]); acc[5] = fmaf(f[1], wv, acc[5]);
        f = __builtin_amdgcn_cvt_pk_f32_fp8((int)v.y, true);
        acc[6] = fmaf(f[0], wv, acc[6]); acc[7] = fmaf(f[1], wv, acc[7]);
    }

    float r[8];
#pragma unroll
    for (int i = 0; i < 8; i++) r[i] = fmaxf(acc[i] + b1[q * 8 + i], 0.f);
    __half2 p0 = __floats2half2_rn(r[0], r[1]);
    __half2 p1 = __floats2half2_rn(r[2], r[3]);
    __half2 p2 = __floats2half2_rn(r[4], r[5]);
    __half2 p3 = __floats2half2_rn(r[6], r[7]);
    uint4 o4;
    o4.x = *(unsigned*)&p0; o4.y = *(unsigned*)&p1;
    o4.z = *(unsigned*)&p2; o4.w = *(unsigned*)&p3;
    *(uint4*)(H2 + (size_t)node * HID + q * 8) = o4;
}

// ---------------- GEMM2 (MFMA fp16, no LDS): Z8 = fp8(H2 @ W2), 64 B rows ----------------

__global__ __launch_bounds__(256) void k_gemm2(const __half* __restrict__ H2,
                                               const __half* __restrict__ W2t,
                                               unsigned char* __restrict__ Z8, int M) {
    int tid = threadIdx.x;
    int wid = tid >> 6, lane = tid & 63;
    int q = lane & 15, kg = lane >> 4;
    int row = blockIdx.x * 64 + wid * 16 + q;
    int lrow = min(row, M - 1);
    const __half* hr = H2 + (size_t)lrow * HID;

    half8_t a[4];
#pragma unroll
    for (int kt = 0; kt < 4; kt++) a[kt] = *(const half8_t*)(hr + kt * 32 + kg * 8);

    f32x4 acc[3];
#pragma unroll
    for (int c = 0; c < 3; c++) acc[c] = (f32x4){0.f, 0.f, 0.f, 0.f};

#pragma unroll
    for (int c = 0; c < 3; c++) {
        const __half* wc = W2t + (size_t)(c * 16 + q) * HID + kg * 8;
#pragma unroll
        for (int kt = 0; kt < 4; kt++) {
            half8_t b = *(const half8_t*)(wc + kt * 32);
            acc[c] = __builtin_amdgcn_mfma_f32_16x16x32_f16(a[kt], b, acc[c], 0, 0, 0);
        }
    }

    int r0 = blockIdx.x * 64 + wid * 16 + kg * 4;
#pragma unroll
    for (int c = 0; c < 3; c++) {
        int col = c * 16 + q;
        if (col < NCLS) {
#pragma unroll
            for (int i = 0; i < 4; i++) {
                int r = r0 + i;
                if (r < M) {
                    int p = __builtin_amdgcn_cvt_pk_fp8_f32(acc[c][i], acc[c][i], 0, false);
                    Z8[(size_t)r * ZPB + col] = (unsigned char)(p & 0xff);
                }
            }
        }
    }
}

// ---------------- agg2 + bias + log_softmax (fp8 Z, 1 line/gather) ----------------
// one 8-lane group per node (32 nodes/block); no cross-group reduction; lanes l>=5
// accumulate row padding into class-slots 40..63 which the softmax discards.

__global__ __launch_bounds__(256) void k_agg2(const unsigned char* __restrict__ Z8,
                                              const unsigned* __restrict__ eew,
                                              const int* __restrict__ off,
                                              const int* __restrict__ cnt,
                                              const float* __restrict__ dinv,
                                              const float* __restrict__ b2,
                                              float* __restrict__ Out, int n) {
    int tid = threadIdx.x;
    int node = blockIdx.x * 32 + (tid >> 3);
    int l = tid & 7;
    if (node >= n) return;
    float di = dinv[node];
    int start = off[node], ne = cnt[node];

    float acc[8];
    {
        uint2 v = *(const uint2*)(Z8 + (size_t)node * ZPB + l * 8);
        float wv = di * di;
        f32x2 f;
        f = __builtin_amdgcn_cvt_pk_f32_fp8((int)v.x, false);
        acc[0] = f[0] * wv; acc[1] = f[1] * wv;
        f = __builtin_amdgcn_cvt_pk_f32_fp8((int)v.x, true);
        acc[2] = f[0] * wv; acc[3] = f[1] * wv;
        f = __builtin_amdgcn_cvt_pk_f32_fp8((int)v.y, false);
        acc[4] = f[0] * wv; acc[5] = f[1] * wv;
        f = __builtin_amdgcn_cvt_pk_f32_fp8((int)v.y, true);
        acc[6] = f[0] * wv; acc[7] = f[1] * wv;
    }

#pragma unroll 2
    for (int j = 0; j < ne; ++j) {
        unsigned u = eew[start + j];          // group-uniform broadcast load
        int s = (int)(u >> 15);
        float wv = __uint_as_float((u & 0x7FFFu) << 17);
        uint2 v = *(const uint2*)(Z8 + (size_t)s * ZPB + l * 8);
        f32x2 f;
        f = __builtin_amdgcn_cvt_pk_f32_fp8((int)v.x, false);
        acc[0] = fmaf(f[0], wv, acc[0]); acc[1] = fmaf(f[1], wv, acc[1]);
        f = __builtin_amdgcn_cvt_pk_f32_fp8((int)v.x, true);
        acc[2] = fmaf(f[0], wv, acc[2]); acc[3] = fmaf(f[1], wv, acc[3]);
        f = __builtin_amdgcn_cvt_pk_f32_fp8((int)v.y, false);
        acc[4] = fmaf(f[0], wv, acc[4]); acc[5] = fmaf(f[1], wv, acc[5]);
        f = __builtin_amdgcn_cvt_pk_f32_fp8((int)v.y, true);
        acc[6] = fmaf(f[0], wv, acc[6]); acc[7] = fmaf(f[1], wv, acc[7]);
    }

    bool valid = (l < 5);
    float v[8];
    float m = -INFINITY;
#pragma unroll
    for (int i = 0; i < 8; i++) {
        v[i] = valid ? acc[i] + b2[l * 8 + i] : -INFINITY;
        m = fmaxf(m, v[i]);
    }
#pragma unroll
    for (int o = 1; o <= 4; o <<= 1) m = fmaxf(m, __shfl_xor(m, o));
    float ssum = 0.f;
#pragma unroll
    for (int i = 0; i < 8; i++)
        if (valid) ssum += __expf(v[i] - m);
#pragma unroll
    for (int o = 1; o <= 4; o <<= 1) ssum += __shfl_xor(ssum, o);
    float lse = m + logf(ssum);

    if (valid) {
        float4 w0 = make_float4(v[0] - lse, v[1] - lse, v[2] - lse, v[3] - lse);
        float4 w1 = make_float4(v[4] - lse, v[5] - lse, v[6] - lse, v[7] - lse);
        float* op = Out + (size_t)node * NCLS + l * 8;
        *(float4*)op = w0;
        *(float4*)(op + 4) = w1;
    }
}

// ---------------- launch ----------------

extern "C" void kernel_launch(void* const* d_in, const int* in_sizes, int n_in,
                              void* d_out, int out_size, void* d_ws, size_t ws_size,
                              hipStream_t stream) {
    const float* x  = (const float*)d_in[0];
    const int* ei   = (const int*)d_in[1];
    const float* W1 = (const float*)d_in[2];
    const float* b1 = (const float*)d_in[3];
    const float* W2 = (const float*)d_in[4];
    const float* b2 = (const float*)d_in[5];
    float* out = (float*)d_out;

    const int n = in_sizes[0] / FIN;   // 100000
    const int E = in_sizes[1] / 2;     // 1600000
    const int* src = ei;
    const int* dst = ei + E;
    const int nbk = (n + BKT_SZ - 1) >> BKT_SHIFT;  // 196

    char* w = (char*)d_ws;
    auto alloc = [&](size_t bytes) {
        char* p = w;
        w += (bytes + 255) & ~(size_t)255;
        return p;
    };
    int* cnt     = (int*)alloc((size_t)n * 4);
    int* off     = (int*)alloc((size_t)n * 4);
    int* bsum    = (int*)alloc(512);
    float* dinv  = (float*)alloc((size_t)n * 4);
    int* boff    = (int*)alloc((size_t)(nbk + 1) * 4);
    int* bcur    = (int*)alloc((size_t)nbk * 4);
    int2* ebkt   = (int2*)alloc((size_t)E * 8);
    unsigned* eew = (unsigned*)alloc((size_t)E * 4);
    ushort* wt   = (ushort*)alloc((size_t)FIN * HID * 2);
    __half* w2t  = (__half*)alloc((size_t)48 * HID * 2);
    unsigned char* H8 = (unsigned char*)alloc((size_t)n * HID);
    __half* H2   = (__half*)alloc((size_t)n * HID * 2);
    unsigned char* Z8 = (unsigned char*)alloc((size_t)n * ZPB);

    const int nb = (n + 1023) / 1024;

    // prep: zero cnt + convert both weight matrices (one kernel)
    k_prep<<<(n + 255) / 256, 256, 0, stream>>>(cnt, W1, wt, W2, w2t, n);

    // CSR: hist + node-level exclusive scan + dinv
    k_hist<<<(E + 255) / 256, 256, 0, stream>>>(dst, E, cnt);
    k_scan1<<<nb, 1024, 0, stream>>>(cnt, off, bsum, n);
    k_scan2<<<1, 64, 0, stream>>>(bsum, nb);
    k_scan3<<<(n + 255) / 256, 256, 0, stream>>>(off, cnt, bsum, dinv, n);

    // two-phase bucket scatter (packs src+weight into 4 B/edge)
    k_binit<<<1, 256, 0, stream>>>(off, boff, bcur, n, E, nbk);
    k_bucketize<<<(E + CHUNK - 1) / CHUNK, 256, 0, stream>>>(src, dst, E, bcur, ebkt, nbk);
    k_sortbkt<<<nbk, 512, 0, stream>>>(ebkt, boff, off, dinv, eew, n);

    // layer 1
    k_gemm1<<<(n + 63) / 64, 256, 0, stream>>>(x, wt, H8, n);
    k_agg1<<<(n + 15) / 16, 256, 0, stream>>>(H8, eew, off, cnt, dinv, b1, H2, n);

    // layer 2 + log_softmax
    k_gemm2<<<(n + 63) / 64, 256, 0, stream>>>(H2, w2t, Z8, n);
    k_agg2<<<(n + 31) / 32, 256, 0, stream>>>(Z8, eew, off, cnt, dinv, b2, out, n);
}

// Round 12
// 171.869 us; speedup vs baseline: 1.7651x; 1.3828x over previous
//
#include <hip/hip_runtime.h>
#include <hip/hip_fp16.h>
#include <math.h>

#define FIN 256
#define HID 128
#define NCLS 40
#define ZPB 64   // fp8 Z row stride in bytes (one cache line)
#define BKT_SHIFT 9
#define BKT_SZ 512
#define CHUNK 2048
#define CAP 12288   // bucket region capacity (mean 8192, sd ~90 -> 45 sd headroom)

typedef __attribute__((ext_vector_type(8))) short short8_t;
typedef __attribute__((ext_vector_type(8))) _Float16 half8_t;
typedef __attribute__((ext_vector_type(4))) float f32x4;
typedef __attribute__((ext_vector_type(2))) float f32x2;

static __device__ __forceinline__ ushort f2bf(float f) {
    unsigned u = __float_as_uint(f);
    u += 0x7FFF + ((u >> 16) & 1);
    return (ushort)(u >> 16);
}

// packed edge: src (17 bits) << 15 | top-15-bits-of-fp32-weight (sign0+exp8+mant6)
static __device__ __forceinline__ unsigned pack_ew(int s, float w) {
    return ((unsigned)s << 15) | (__float_as_uint(w) >> 17);
}

// ---------------- prep: zero bucket cursors + convert W1 (bf16^T) + W2 (f16^T padded) ----------------

__global__ void k_prep(int* __restrict__ bcur, const float* __restrict__ W1,
                       ushort* __restrict__ Wt, const float* __restrict__ W2,
                       __half* __restrict__ W2t, int nbk) {
    int i = blockIdx.x * 256 + threadIdx.x;
    if (i < nbk) bcur[i] = 0;
    if (i < FIN * HID) {
        int c = i >> 8, k = i & 255;
        Wt[i] = f2bf(W1[(size_t)k * HID + c]);
    }
    if (i < 48 * HID) {
        int c = i >> 7, k = i & 127;
        W2t[i] = __float2half((c < NCLS) ? W2[(size_t)k * NCLS + c] : 0.f);
    }
}

// ---------------- phase 1: bucketize edges by dst>>9 into fixed-capacity regions ----------------

__global__ __launch_bounds__(256) void k_bucketize(const int* __restrict__ src,
                                                   const int* __restrict__ dst, int E,
                                                   int* __restrict__ bcur,
                                                   int2* __restrict__ ebkt, int nbk) {
    __shared__ int hist[256];
    __shared__ int scanb[256];
    __shared__ int base[256];
    __shared__ int gbase[256];
    __shared__ int2 stage[CHUNK];
    int t = threadIdx.x;
    int e0 = blockIdx.x * CHUNK;
    int cntc = min(CHUNK, E - e0);
    hist[t] = 0;
    __syncthreads();

    int s_[8], d_[8], bk_[8], rk_[8];
#pragma unroll
    for (int i = 0; i < 8; i++) {
        int j = t + i * 256;
        if (j < cntc) {
            int s = src[e0 + j], d = dst[e0 + j];
            s_[i] = s; d_[i] = d;
            bk_[i] = d >> BKT_SHIFT;
            rk_[i] = atomicAdd(&hist[bk_[i]], 1);
        } else {
            bk_[i] = -1;
        }
    }
    __syncthreads();

    scanb[t] = hist[t];
    __syncthreads();
    for (int o = 1; o < 256; o <<= 1) {
        int u = (t >= o) ? scanb[t - o] : 0;
        __syncthreads();
        scanb[t] += u;
        __syncthreads();
    }
    base[t] = scanb[t] - hist[t];
    if (t < nbk && hist[t] > 0) gbase[t] = atomicAdd(&bcur[t], hist[t]);
    __syncthreads();

#pragma unroll
    for (int i = 0; i < 8; i++) {
        if (bk_[i] >= 0) stage[base[bk_[i]] + rk_[i]] = make_int2(s_[i], d_[i]);
    }
    __syncthreads();

#pragma unroll
    for (int i = 0; i < 8; i++) {
        int j = t + i * 256;
        if (j < cntc) {
            int2 e = stage[j];
            int bk = e.y >> BKT_SHIFT;
            ebkt[(size_t)bk * CAP + gbase[bk] + (j - base[bk])] = e;
        }
    }
}

// ---------------- bucket-size exclusive scan (196 values, 1 block) ----------------

__global__ void k_bscan(const int* __restrict__ bcur, int* __restrict__ bbase, int nbk) {
    __shared__ int sm[256];
    int t = threadIdx.x;
    int v = (t < nbk) ? bcur[t] : 0;
    sm[t] = v;
    __syncthreads();
    for (int o = 1; o < 256; o <<= 1) {
        int u = (t >= o) ? sm[t - o] : 0;
        __syncthreads();
        sm[t] += u;
        __syncthreads();
    }
    if (t < nbk) bbase[t] = sm[t] - v;
}

// ---------------- per-bucket LDS histogram + scan -> off, cnt, dinv ----------------

__global__ __launch_bounds__(512) void k_cnt(const int2* __restrict__ ebkt,
                                             const int* __restrict__ bcur,
                                             const int* __restrict__ bbase,
                                             int* __restrict__ off, int* __restrict__ cnt,
                                             float* __restrict__ dinv, int n) {
    __shared__ int lcnt[BKT_SZ];
    __shared__ int lofs[BKT_SZ];
    int b = blockIdx.x, t = threadIdx.x;
    int n0 = b << BKT_SHIFT;
    lcnt[t] = 0;
    __syncthreads();
    int sz = bcur[b];
    const int2* ep = ebkt + (size_t)b * CAP;
    for (int e = t; e < sz; e += 512) atomicAdd(&lcnt[ep[e].y - n0], 1);
    __syncthreads();
    lofs[t] = lcnt[t];
    __syncthreads();
    for (int o = 1; o < 512; o <<= 1) {
        int u = (t >= o) ? lofs[t - o] : 0;
        __syncthreads();
        lofs[t] += u;
        __syncthreads();
    }
    int node = n0 + t;
    if (node < n) {
        int c = lcnt[t];
        off[node] = bbase[b] + lofs[t] - c;
        cnt[node] = c;
        dinv[node] = rsqrtf((float)(c + 1));
    }
}

// ---------------- per-bucket placement: pack (src, weight) via LDS cursors ----------------

__global__ __launch_bounds__(512) void k_place(const int2* __restrict__ ebkt,
                                               const int* __restrict__ bcur,
                                               const int* __restrict__ off,
                                               const float* __restrict__ dinv,
                                               unsigned* __restrict__ eew, int n) {
    __shared__ int curx[BKT_SZ];
    __shared__ float ldin[BKT_SZ];
    int b = blockIdx.x, t = threadIdx.x;
    int n0 = b << BKT_SHIFT;
    int node = n0 + t;
    if (node < n) {
        curx[t] = off[node];
        ldin[t] = dinv[node];
    }
    __syncthreads();
    int sz = bcur[b];
    const int2* ep = ebkt + (size_t)b * CAP;
    for (int e = t; e < sz; e += 512) {
        int2 ed = ep[e];
        int s = ed.x, dl = ed.y - n0;
        float w = dinv[s] * ldin[dl];
        int pos = atomicAdd(&curx[dl], 1);
        eew[pos] = pack_ew(s, w);
    }
}

// ---------------- GEMM1 (MFMA bf16): H8 = fp8(X @ W1), x prefetched ----------------

__global__ __launch_bounds__(256) void k_gemm1(const float* __restrict__ X,
                                               const ushort* __restrict__ Wt,
                                               unsigned char* __restrict__ H8, int M) {
    __shared__ uint4 wlds[128 * 32];  // 64 KB; reused as f32 staging in epilogue
    int tid = threadIdx.x;
    const uint4* wg = (const uint4*)Wt;
#pragma unroll
    for (int i = 0; i < 16; i++) {
        int e = tid + i * 256;
        int r = e >> 5, ch = e & 31;
        wlds[r * 32 + (ch ^ (r & 7))] = wg[e];
    }

    int wid = tid >> 6, lane = tid & 63;
    int q = lane & 15, kg = lane >> 4;
    int grow_in = blockIdx.x * 64 + wid * 16 + q;
    int lrow = min(grow_in, M - 1);
    const float* xr = X + (size_t)lrow * FIN;

    float4 xf0[8], xf1[8];
#pragma unroll
    for (int kt = 0; kt < 8; kt++) {
        int k0 = kt * 32 + kg * 8;
        xf0[kt] = *(const float4*)(xr + k0);
        xf1[kt] = *(const float4*)(xr + k0 + 4);
    }
    __syncthreads();

    f32x4 acc[8];
#pragma unroll
    for (int c = 0; c < 8; c++) acc[c] = (f32x4){0.f, 0.f, 0.f, 0.f};

#pragma unroll
    for (int kt = 0; kt < 8; kt++) {
        unsigned r0, r1, r2, r3;
        asm("v_cvt_pk_bf16_f32 %0, %1, %2" : "=v"(r0) : "v"(xf0[kt].x), "v"(xf0[kt].y));
        asm("v_cvt_pk_bf16_f32 %0, %1, %2" : "=v"(r1) : "v"(xf0[kt].z), "v"(xf0[kt].w));
        asm("v_cvt_pk_bf16_f32 %0, %1, %2" : "=v"(r2) : "v"(xf1[kt].x), "v"(xf1[kt].y));
        asm("v_cvt_pk_bf16_f32 %0, %1, %2" : "=v"(r3) : "v"(xf1[kt].z), "v"(xf1[kt].w));
        union { uint4 u; short8_t s; } cv;
        cv.u = make_uint4(r0, r1, r2, r3);
        short8_t a = cv.s;
        int ch = kt * 4 + kg;
#pragma unroll
        for (int c = 0; c < 8; c++) {
            int col = c * 16 + q;
            short8_t b = *(const short8_t*)&wlds[col * 32 + (ch ^ (col & 7))];
            acc[c] = __builtin_amdgcn_mfma_f32_16x16x32_bf16(a, b, acc[c], 0, 0, 0);
        }
    }

    __syncthreads();
    float* st = (float*)wlds;  // [64][132]
#pragma unroll
    for (int c = 0; c < 8; c++) {
        int col = c * 16 + q;
#pragma unroll
        for (int i = 0; i < 4; i++) {
            int lr = wid * 16 + kg * 4 + i;
            st[lr * 132 + col] = acc[c][i];
        }
    }
    __syncthreads();
    int orow = tid >> 2, seg = tid & 3;
    int grow = blockIdx.x * 64 + orow;
    if (grow < M) {
        const float* sp = st + orow * 132 + seg * 32;
        unsigned u[8];
#pragma unroll
        for (int k = 0; k < 8; k++) {
            int p = 0;
            p = __builtin_amdgcn_cvt_pk_fp8_f32(sp[4 * k + 0], sp[4 * k + 1], p, false);
            p = __builtin_amdgcn_cvt_pk_fp8_f32(sp[4 * k + 2], sp[4 * k + 3], p, true);
            u[k] = (unsigned)p;
        }
        uint4* op = (uint4*)(H8 + (size_t)grow * HID + seg * 32);
        op[0] = make_uint4(u[0], u[1], u[2], u[3]);
        op[1] = make_uint4(u[4], u[5], u[6], u[7]);
    }
}

// ---------------- agg1: H2 = fp16(relu(b1 + sum w*H8[s])) ----------------
// one 16-lane group per node (16 nodes/block); no cross-group reduction

__global__ __launch_bounds__(256) void k_agg1(const unsigned char* __restrict__ H8,
                                              const unsigned* __restrict__ eew,
                                              const int* __restrict__ off,
                                              const int* __restrict__ cnt,
                                              const float* __restrict__ dinv,
                                              const float* __restrict__ b1,
                                              __half* __restrict__ H2, int n) {
    int tid = threadIdx.x;
    int node = blockIdx.x * 16 + (tid >> 4);
    int q = tid & 15;
    if (node >= n) return;
    float di = dinv[node];
    int start = off[node], ne = cnt[node];

    // self-loop
    float acc[8];
    {
        uint2 v = *(const uint2*)(H8 + (size_t)node * HID + q * 8);
        float wv = di * di;
        f32x2 f;
        f = __builtin_amdgcn_cvt_pk_f32_fp8((int)v.x, false);
        acc[0] = f[0] * wv; acc[1] = f[1] * wv;
        f = __builtin_amdgcn_cvt_pk_f32_fp8((int)v.x, true);
        acc[2] = f[0] * wv; acc[3] = f[1] * wv;
        f = __builtin_amdgcn_cvt_pk_f32_fp8((int)v.y, false);
        acc[4] = f[0] * wv; acc[5] = f[1] * wv;
        f = __builtin_amdgcn_cvt_pk_f32_fp8((int)v.y, true);
        acc[6] = f[0] * wv; acc[7] = f[1] * wv;
    }

#pragma unroll 2
    for (int j = 0; j < ne; ++j) {
        unsigned u = eew[start + j];          // group-uniform broadcast load
        int s = (int)(u >> 15);
        float wv = __uint_as_float((u & 0x7FFFu) << 17);
        uint2 v = *(const uint2*)(H8 + (size_t)s * HID + q * 8);
        f32x2 f;
        f = __builtin_amdgcn_cvt_pk_f32_fp8((int)v.x, false);
        acc[0] = fmaf(f[0], wv, acc[0]); acc[1] = fmaf(f[1], wv, acc[1]);
        f = __builtin_amdgcn_cvt_pk_f32_fp8((int)v.x, true);
        acc[2] = fmaf(f[0], wv, acc[2]); acc[3] = fmaf(f[1], wv, acc[3]);
        f = __builtin_amdgcn_cvt_pk_f32_fp8((int)v.y, false);
        acc[4] = fmaf(f[0], wv, acc[4]); acc[5] = fmaf(f[1], wv, acc[5]);
        f = __builtin_amdgcn_cvt_pk_f32_fp8((int)v.y, true);
        acc[6] = fmaf(f[0], wv, acc[6]); acc[7] = fmaf(f[1], wv, acc[7]);
    }

    float r[8];
#pragma unroll
    for (int i = 0; i < 8; i++) r[i] = fmaxf(acc[i] + b1[q * 8 + i], 0.f);
    __half2 p0 = __floats2half2_rn(r[0], r[1]);
    __half2 p1 = __floats2half2_rn(r[2], r[3]);
    __half2 p2 = __floats2half2_rn(r[4], r[5]);
    __half2 p3 = __floats2half2_rn(r[6], r[7]);
    uint4 o4;
    o4.x = *(unsigned*)&p0; o4.y = *(unsigned*)&p1;
    o4.z = *(unsigned*)&p2; o4.w = *(unsigned*)&p3;
    *(uint4*)(H2 + (size_t)node * HID + q * 8) = o4;
}

// ---------------- GEMM2 (MFMA fp16, no LDS): Z8 = fp8(H2 @ W2), 64 B rows ----------------

__global__ __launch_bounds__(256) void k_gemm2(const __half* __restrict__ H2,
                                               const __half* __restrict__ W2t,
                                               unsigned char* __restrict__ Z8, int M) {
    int tid = threadIdx.x;
    int wid = tid >> 6, lane = tid & 63;
    int q = lane & 15, kg = lane >> 4;
    int row = blockIdx.x * 64 + wid * 16 + q;
    int lrow = min(row, M - 1);
    const __half* hr = H2 + (size_t)lrow * HID;

    half8_t a[4];
#pragma unroll
    for (int kt = 0; kt < 4; kt++) a[kt] = *(const half8_t*)(hr + kt * 32 + kg * 8);

    f32x4 acc[3];
#pragma unroll
    for (int c = 0; c < 3; c++) acc[c] = (f32x4){0.f, 0.f, 0.f, 0.f};

#pragma unroll
    for (int c = 0; c < 3; c++) {
        const __half* wc = W2t + (size_t)(c * 16 + q) * HID + kg * 8;
#pragma unroll
        for (int kt = 0; kt < 4; kt++) {
            half8_t b = *(const half8_t*)(wc + kt * 32);
            acc[c] = __builtin_amdgcn_mfma_f32_16x16x32_f16(a[kt], b, acc[c], 0, 0, 0);
        }
    }

    int r0 = blockIdx.x * 64 + wid * 16 + kg * 4;
#pragma unroll
    for (int c = 0; c < 3; c++) {
        int col = c * 16 + q;
        if (col < NCLS) {
#pragma unroll
            for (int i = 0; i < 4; i++) {
                int r = r0 + i;
                if (r < M) {
                    int p = __builtin_amdgcn_cvt_pk_fp8_f32(acc[c][i], acc[c][i], 0, false);
                    Z8[(size_t)r * ZPB + col] = (unsigned char)(p & 0xff);
                }
            }
        }
    }
}

// ---------------- agg2 + bias + log_softmax (fp8 Z, 1 line/gather) ----------------
// one 8-lane group per node (32 nodes/block); lanes l>=5 accumulate row padding
// into class-slots 40..63 which the softmax discards.

__global__ __launch_bounds__(256) void k_agg2(const unsigned char* __restrict__ Z8,
                                              const unsigned* __restrict__ eew,
                                              const int* __restrict__ off,
                                              const int* __restrict__ cnt,
                                              const float* __restrict__ dinv,
                                              const float* __restrict__ b2,
                                              float* __restrict__ Out, int n) {
    int tid = threadIdx.x;
    int node = blockIdx.x * 32 + (tid >> 3);
    int l = tid & 7;
    if (node >= n) return;
    float di = dinv[node];
    int start = off[node], ne = cnt[node];

    float acc[8];
    {
        uint2 v = *(const uint2*)(Z8 + (size_t)node * ZPB + l * 8);
        float wv = di * di;
        f32x2 f;
        f = __builtin_amdgcn_cvt_pk_f32_fp8((int)v.x, false);
        acc[0] = f[0] * wv; acc[1] = f[1] * wv;
        f = __builtin_amdgcn_cvt_pk_f32_fp8((int)v.x, true);
        acc[2] = f[0] * wv; acc[3] = f[1] * wv;
        f = __builtin_amdgcn_cvt_pk_f32_fp8((int)v.y, false);
        acc[4] = f[0] * wv; acc[5] = f[1] * wv;
        f = __builtin_amdgcn_cvt_pk_f32_fp8((int)v.y, true);
        acc[6] = f[0] * wv; acc[7] = f[1] * wv;
    }

#pragma unroll 2
    for (int j = 0; j < ne; ++j) {
        unsigned u = eew[start + j];          // group-uniform broadcast load
        int s = (int)(u >> 15);
        float wv = __uint_as_float((u & 0x7FFFu) << 17);
        uint2 v = *(const uint2*)(Z8 + (size_t)s * ZPB + l * 8);
        f32x2 f;
        f = __builtin_amdgcn_cvt_pk_f32_fp8((int)v.x, false);
        acc[0] = fmaf(f[0], wv, acc[0]); acc[1] = fmaf(f[1], wv, acc[1]);
        f = __builtin_amdgcn_cvt_pk_f32_fp8((int)v.x, true);
        acc[2] = fmaf(f[0], wv, acc[2]); acc[3] = fmaf(f[1], wv, acc[3]);
        f = __builtin_amdgcn_cvt_pk_f32_fp8((int)v.y, false);
        acc[4] = fmaf(f[0], wv, acc[4]); acc[5] = fmaf(f[1], wv, acc[5]);
        f = __builtin_amdgcn_cvt_pk_f32_fp8((int)v.y, true);
        acc[6] = fmaf(f[0], wv, acc[6]); acc[7] = fmaf(f[1], wv, acc[7]);
    }

    bool valid = (l < 5);
    float v[8];
    float m = -INFINITY;
#pragma unroll
    for (int i = 0; i < 8; i++) {
        v[i] = valid ? acc[i] + b2[l * 8 + i] : -INFINITY;
        m = fmaxf(m, v[i]);
    }
#pragma unroll
    for (int o = 1; o <= 4; o <<= 1) m = fmaxf(m, __shfl_xor(m, o));
    float ssum = 0.f;
#pragma unroll
    for (int i = 0; i < 8; i++)
        if (valid) ssum += __expf(v[i] - m);
#pragma unroll
    for (int o = 1; o <= 4; o <<= 1) ssum += __shfl_xor(ssum, o);
    float lse = m + logf(ssum);

    if (valid) {
        float4 w0 = make_float4(v[0] - lse, v[1] - lse, v[2] - lse, v[3] - lse);
        float4 w1 = make_float4(v[4] - lse, v[5] - lse, v[6] - lse, v[7] - lse);
        float* op = Out + (size_t)node * NCLS + l * 8;
        *(float4*)op = w0;
        *(float4*)(op + 4) = w1;
    }
}

// ---------------- launch ----------------

extern "C" void kernel_launch(void* const* d_in, const int* in_sizes, int n_in,
                              void* d_out, int out_size, void* d_ws, size_t ws_size,
                              hipStream_t stream) {
    const float* x  = (const float*)d_in[0];
    const int* ei   = (const int*)d_in[1];
    const float* W1 = (const float*)d_in[2];
    const float* b1 = (const float*)d_in[3];
    const float* W2 = (const float*)d_in[4];
    const float* b2 = (const float*)d_in[5];
    float* out = (float*)d_out;

    const int n = in_sizes[0] / FIN;   // 100000
    const int E = in_sizes[1] / 2;     // 1600000
    const int* src = ei;
    const int* dst = ei + E;
    const int nbk = (n + BKT_SZ - 1) >> BKT_SHIFT;  // 196

    char* w = (char*)d_ws;
    auto alloc = [&](size_t bytes) {
        char* p = w;
        w += (bytes + 255) & ~(size_t)255;
        return p;
    };
    int* off     = (int*)alloc((size_t)n * 4);
    int* cnt     = (int*)alloc((size_t)n * 4);
    float* dinv  = (float*)alloc((size_t)n * 4);
    int* bcur    = (int*)alloc((size_t)nbk * 4);
    int* bbase   = (int*)alloc((size_t)nbk * 4);
    int2* ebkt   = (int2*)alloc((size_t)nbk * CAP * 8);
    unsigned* eew = (unsigned*)alloc((size_t)E * 4);
    ushort* wt   = (ushort*)alloc((size_t)FIN * HID * 2);
    __half* w2t  = (__half*)alloc((size_t)48 * HID * 2);
    unsigned char* H8 = (unsigned char*)alloc((size_t)n * HID);
    __half* H2   = (__half*)alloc((size_t)n * HID * 2);
    unsigned char* Z8 = (unsigned char*)alloc((size_t)n * ZPB);

    // prep: zero bucket cursors + convert both weight matrices
    k_prep<<<(FIN * HID) / 256, 256, 0, stream>>>(bcur, W1, wt, W2, w2t, nbk);

    // CSR build, bucket-local (no global atomics on nodes, no n-wide scan)
    k_bucketize<<<(E + CHUNK - 1) / CHUNK, 256, 0, stream>>>(src, dst, E, bcur, ebkt, nbk);
    k_bscan<<<1, 256, 0, stream>>>(bcur, bbase, nbk);
    k_cnt<<<nbk, 512, 0, stream>>>(ebkt, bcur, bbase, off, cnt, dinv, n);
    k_place<<<nbk, 512, 0, stream>>>(ebkt, bcur, off, dinv, eew, n);

    // layer 1
    k_gemm1<<<(n + 63) / 64, 256, 0, stream>>>(x, wt, H8, n);
    k_agg1<<<(n + 15) / 16, 256, 0, stream>>>(H8, eew, off, cnt, dinv, b1, H2, n);

    // layer 2 + log_softmax
    k_gemm2<<<(n + 63) / 64, 256, 0, stream>>>(H2, w2t, Z8, n);
    k_agg2<<<(n + 31) / 32, 256, 0, stream>>>(Z8, eew, off, cnt, dinv, b2, out, n);
}

// Round 13
// 163.815 us; speedup vs baseline: 1.8519x; 1.0492x over previous
//
#include <hip/hip_runtime.h>
#include <hip/hip_fp16.h>
#include <math.h>

#define FIN 256
#define HID 128
#define NCLS 40
#define ZPB 64   // fp8 Z row stride in bytes (one cache line)
#define BKT_SHIFT 9
#define BKT_SZ 512
#define CHUNK 2048
#define CAP 12288   // bucket region capacity (mean 8192, sd ~90 -> 45 sd headroom)

typedef __attribute__((ext_vector_type(8))) short short8_t;
typedef __attribute__((ext_vector_type(8))) _Float16 half8_t;
typedef __attribute__((ext_vector_type(4))) float f32x4;
typedef __attribute__((ext_vector_type(2))) float f32x2;

static __device__ __forceinline__ ushort f2bf(float f) {
    unsigned u = __float_as_uint(f);
    u += 0x7FFF + ((u >> 16) & 1);
    return (ushort)(u >> 16);
}

// packed edge (eew): src (17 bits) << 15 | top-15-bits-of-fp32-weight
static __device__ __forceinline__ unsigned pack_ew(int s, float w) {
    return ((unsigned)s << 15) | (__float_as_uint(w) >> 17);
}

// ---------------- prep: zero bucket cursors + ticket + convert W1/W2 ----------------

__global__ void k_prep(int* __restrict__ bcur, const float* __restrict__ W1,
                       ushort* __restrict__ Wt, const float* __restrict__ W2,
                       __half* __restrict__ W2t, int nbk) {
    int i = blockIdx.x * 256 + threadIdx.x;
    if (i <= nbk) bcur[i] = 0;   // bcur[nbk] doubles as the global base ticket
    if (i < FIN * HID) {
        int c = i >> 8, k = i & 255;
        Wt[i] = f2bf(W1[(size_t)k * HID + c]);
    }
    if (i < 48 * HID) {
        int c = i >> 7, k = i & 127;
        W2t[i] = __float2half((c < NCLS) ? W2[(size_t)k * NCLS + c] : 0.f);
    }
}

// ---------------- fused: bucketize (blocks [0,nbkb)) + GEMM1 (rest) ----------------
// bucketize: partition edges by dst>>9 into fixed-capacity u32 regions
// gemm1: H8 = fp8(X @ W1) via MFMA bf16, LDS-transpose epilogue

__global__ __launch_bounds__(256) void k_g1bkt(const float* __restrict__ X,
                                               const ushort* __restrict__ Wt,
                                               unsigned char* __restrict__ H8, int M,
                                               const int* __restrict__ src,
                                               const int* __restrict__ dst, int E,
                                               int* __restrict__ bcur,
                                               unsigned* __restrict__ ebkt,
                                               int nbk, int nbkb) {
    __shared__ uint4 wlds[128 * 32];  // 64 KB union: gemm1 W-tile / bucketize scratch
    int tid = threadIdx.x;

    if ((int)blockIdx.x < nbkb) {
        // ---- bucketize body ----
        int* hist  = (int*)wlds;         // 256
        int* scanb = hist + 256;         // 256
        int* base  = scanb + 256;        // 256
        int* gbase = base + 256;         // 256
        unsigned* stage = (unsigned*)(gbase + 256);       // CHUNK
        unsigned char* sbk = (unsigned char*)(stage + CHUNK);  // CHUNK
        int e0 = blockIdx.x * CHUNK;
        int cntc = min(CHUNK, E - e0);
        hist[tid] = 0;
        __syncthreads();

        int s_[8], d_[8], bk_[8], rk_[8];
#pragma unroll
        for (int i = 0; i < 8; i++) {
            int j = tid + i * 256;
            if (j < cntc) {
                int s = src[e0 + j], d = dst[e0 + j];
                s_[i] = s; d_[i] = d;
                bk_[i] = d >> BKT_SHIFT;
                rk_[i] = atomicAdd(&hist[bk_[i]], 1);
            } else {
                bk_[i] = -1;
            }
        }
        __syncthreads();

        scanb[tid] = hist[tid];
        __syncthreads();
        for (int o = 1; o < 256; o <<= 1) {
            int u = (tid >= o) ? scanb[tid - o] : 0;
            __syncthreads();
            scanb[tid] += u;
            __syncthreads();
        }
        base[tid] = scanb[tid] - hist[tid];
        if (tid < nbk && hist[tid] > 0) gbase[tid] = atomicAdd(&bcur[tid], hist[tid]);
        __syncthreads();

#pragma unroll
        for (int i = 0; i < 8; i++) {
            if (bk_[i] >= 0) {
                int p = base[bk_[i]] + rk_[i];
                stage[p] = ((unsigned)s_[i] << 9) | ((unsigned)d_[i] & 511u);
                sbk[p] = (unsigned char)bk_[i];
            }
        }
        __syncthreads();

#pragma unroll
        for (int i = 0; i < 8; i++) {
            int j = tid + i * 256;
            if (j < cntc) {
                int bk = sbk[j];
                ebkt[(size_t)bk * CAP + gbase[bk] + (j - base[bk])] = stage[j];
            }
        }
        return;
    }

    // ---- gemm1 body ----
    int bid = blockIdx.x - nbkb;
    const uint4* wg = (const uint4*)Wt;
#pragma unroll
    for (int i = 0; i < 16; i++) {
        int e = tid + i * 256;
        int r = e >> 5, ch = e & 31;
        wlds[r * 32 + (ch ^ (r & 7))] = wg[e];
    }

    int wid = tid >> 6, lane = tid & 63;
    int q = lane & 15, kg = lane >> 4;
    int grow_in = bid * 64 + wid * 16 + q;
    int lrow = min(grow_in, M - 1);
    const float* xr = X + (size_t)lrow * FIN;

    float4 xf0[8], xf1[8];
#pragma unroll
    for (int kt = 0; kt < 8; kt++) {
        int k0 = kt * 32 + kg * 8;
        xf0[kt] = *(const float4*)(xr + k0);
        xf1[kt] = *(const float4*)(xr + k0 + 4);
    }
    __syncthreads();

    f32x4 acc[8];
#pragma unroll
    for (int c = 0; c < 8; c++) acc[c] = (f32x4){0.f, 0.f, 0.f, 0.f};

#pragma unroll
    for (int kt = 0; kt < 8; kt++) {
        unsigned r0, r1, r2, r3;
        asm("v_cvt_pk_bf16_f32 %0, %1, %2" : "=v"(r0) : "v"(xf0[kt].x), "v"(xf0[kt].y));
        asm("v_cvt_pk_bf16_f32 %0, %1, %2" : "=v"(r1) : "v"(xf0[kt].z), "v"(xf0[kt].w));
        asm("v_cvt_pk_bf16_f32 %0, %1, %2" : "=v"(r2) : "v"(xf1[kt].x), "v"(xf1[kt].y));
        asm("v_cvt_pk_bf16_f32 %0, %1, %2" : "=v"(r3) : "v"(xf1[kt].z), "v"(xf1[kt].w));
        union { uint4 u; short8_t s; } cv;
        cv.u = make_uint4(r0, r1, r2, r3);
        short8_t a = cv.s;
        int ch = kt * 4 + kg;
#pragma unroll
        for (int c = 0; c < 8; c++) {
            int col = c * 16 + q;
            short8_t b = *(const short8_t*)&wlds[col * 32 + (ch ^ (col & 7))];
            acc[c] = __builtin_amdgcn_mfma_f32_16x16x32_bf16(a, b, acc[c], 0, 0, 0);
        }
    }

    __syncthreads();
    float* st = (float*)wlds;  // [64][132]
#pragma unroll
    for (int c = 0; c < 8; c++) {
        int col = c * 16 + q;
#pragma unroll
        for (int i = 0; i < 4; i++) {
            int lr = wid * 16 + kg * 4 + i;
            st[lr * 132 + col] = acc[c][i];
        }
    }
    __syncthreads();
    int orow = tid >> 2, seg = tid & 3;
    int grow = bid * 64 + orow;
    if (grow < M) {
        const float* sp = st + orow * 132 + seg * 32;
        unsigned u[8];
#pragma unroll
        for (int k = 0; k < 8; k++) {
            int p = 0;
            p = __builtin_amdgcn_cvt_pk_fp8_f32(sp[4 * k + 0], sp[4 * k + 1], p, false);
            p = __builtin_amdgcn_cvt_pk_fp8_f32(sp[4 * k + 2], sp[4 * k + 3], p, true);
            u[k] = (unsigned)p;
        }
        uint4* op = (uint4*)(H8 + (size_t)grow * HID + seg * 32);
        op[0] = make_uint4(u[0], u[1], u[2], u[3]);
        op[1] = make_uint4(u[4], u[5], u[6], u[7]);
    }
}

// ---------------- per-bucket LDS histogram + scan -> off, cnt, dinv ----------------
// bucket base allocated via global atomic ticket (any partition of eew is valid)

__global__ __launch_bounds__(512) void k_cnt(const unsigned* __restrict__ ebkt,
                                             int* __restrict__ bcur, int nbk,
                                             int* __restrict__ off, int* __restrict__ cnt,
                                             float* __restrict__ dinv, int n) {
    __shared__ int lcnt[BKT_SZ];
    __shared__ int lofs[BKT_SZ];
    __shared__ int lbase;
    int b = blockIdx.x, t = threadIdx.x;
    int n0 = b << BKT_SHIFT;
    lcnt[t] = 0;
    __syncthreads();
    int sz = bcur[b];
    const unsigned* ep = ebkt + (size_t)b * CAP;
    for (int e = t; e < sz; e += 512) atomicAdd(&lcnt[ep[e] & 511u], 1);
    __syncthreads();
    if (t == 0) lbase = atomicAdd(&bcur[nbk], sz);
    lofs[t] = lcnt[t];
    __syncthreads();
    for (int o = 1; o < 512; o <<= 1) {
        int u = (t >= o) ? lofs[t - o] : 0;
        __syncthreads();
        lofs[t] += u;
        __syncthreads();
    }
    int node = n0 + t;
    if (node < n) {
        int c = lcnt[t];
        off[node] = lbase + lofs[t] - c;
        cnt[node] = c;
        dinv[node] = rsqrtf((float)(c + 1));
    }
}

// ---------------- per-bucket placement: pack (src, weight) via LDS cursors ----------------

__global__ __launch_bounds__(512) void k_place(const unsigned* __restrict__ ebkt,
                                               const int* __restrict__ bcur,
                                               const int* __restrict__ off,
                                               const float* __restrict__ dinv,
                                               unsigned* __restrict__ eew, int n) {
    __shared__ int curx[BKT_SZ];
    __shared__ float ldin[BKT_SZ];
    int b = blockIdx.x, t = threadIdx.x;
    int n0 = b << BKT_SHIFT;
    int node = n0 + t;
    if (node < n) {
        curx[t] = off[node];
        ldin[t] = dinv[node];
    }
    __syncthreads();
    int sz = bcur[b];
    const unsigned* ep = ebkt + (size_t)b * CAP;
    for (int e = t; e < sz; e += 512) {
        unsigned ed = ep[e];
        int s = (int)(ed >> 9), dl = (int)(ed & 511u);
        float w = dinv[s] * ldin[dl];
        int pos = atomicAdd(&curx[dl], 1);
        eew[pos] = pack_ew(s, w);
    }
}

// ---------------- agg1: H2 = fp16(relu(b1 + sum w*H8[s])) ----------------
// one 16-lane group per node (16 nodes/block); no cross-group reduction

__global__ __launch_bounds__(256) void k_agg1(const unsigned char* __restrict__ H8,
                                              const unsigned* __restrict__ eew,
                                              const int* __restrict__ off,
                                              const int* __restrict__ cnt,
                                              const float* __restrict__ dinv,
                                              const float* __restrict__ b1,
                                              __half* __restrict__ H2, int n) {
    int tid = threadIdx.x;
    int node = blockIdx.x * 16 + (tid >> 4);
    int q = tid & 15;
    if (node >= n) return;
    float di = dinv[node];
    int start = off[node], ne = cnt[node];

    float acc[8];
    {
        uint2 v = *(const uint2*)(H8 + (size_t)node * HID + q * 8);
        float wv = di * di;
        f32x2 f;
        f = __builtin_amdgcn_cvt_pk_f32_fp8((int)v.x, false);
        acc[0] = f[0] * wv; acc[1] = f[1] * wv;
        f = __builtin_amdgcn_cvt_pk_f32_fp8((int)v.x, true);
        acc[2] = f[0] * wv; acc[3] = f[1] * wv;
        f = __builtin_amdgcn_cvt_pk_f32_fp8((int)v.y, false);
        acc[4] = f[0] * wv; acc[5] = f[1] * wv;
        f = __builtin_amdgcn_cvt_pk_f32_fp8((int)v.y, true);
        acc[6] = f[0] * wv; acc[7] = f[1] * wv;
    }

#pragma unroll 2
    for (int j = 0; j < ne; ++j) {
        unsigned u = eew[start + j];          // group-uniform broadcast load
        int s = (int)(u >> 15);
        float wv = __uint_as_float((u & 0x7FFFu) << 17);
        uint2 v = *(const uint2*)(H8 + (size_t)s * HID + q * 8);
        f32x2 f;
        f = __builtin_amdgcn_cvt_pk_f32_fp8((int)v.x, false);
        acc[0] = fmaf(f[0], wv, acc[0]); acc[1] = fmaf(f[1], wv, acc[1]);
        f = __builtin_amdgcn_cvt_pk_f32_fp8((int)v.x, true);
        acc[2] = fmaf(f[0], wv, acc[2]); acc[3] = fmaf(f[1], wv, acc[3]);
        f = __builtin_amdgcn_cvt_pk_f32_fp8((int)v.y, false);
        acc[4] = fmaf(f[0], wv, acc[4]); acc[5] = fmaf(f[1], wv, acc[5]);
        f = __builtin_amdgcn_cvt_pk_f32_fp8((int)v.y, true);
        acc[6] = fmaf(f[0], wv, acc[6]); acc[7] = fmaf(f[1], wv, acc[7]);
    }

    float r[8];
#pragma unroll
    for (int i = 0; i < 8; i++) r[i] = fmaxf(acc[i] + b1[q * 8 + i], 0.f);
    __half2 p0 = __floats2half2_rn(r[0], r[1]);
    __half2 p1 = __floats2half2_rn(r[2], r[3]);
    __half2 p2 = __floats2half2_rn(r[4], r[5]);
    __half2 p3 = __floats2half2_rn(r[6], r[7]);
    uint4 o4;
    o4.x = *(unsigned*)&p0; o4.y = *(unsigned*)&p1;
    o4.z = *(unsigned*)&p2; o4.w = *(unsigned*)&p3;
    *(uint4*)(H2 + (size_t)node * HID + q * 8) = o4;
}

// ---------------- GEMM2 (MFMA fp16, no LDS): Z8 = fp8(H2 @ W2), 64 B rows ----------------

__global__ __launch_bounds__(256) void k_gemm2(const __half* __restrict__ H2,
                                               const __half* __restrict__ W2t,
                                               unsigned char* __restrict__ Z8, int M) {
    int tid = threadIdx.x;
    int wid = tid >> 6, lane = tid & 63;
    int q = lane & 15, kg = lane >> 4;
    int row = blockIdx.x * 64 + wid * 16 + q;
    int lrow = min(row, M - 1);
    const __half* hr = H2 + (size_t)lrow * HID;

    half8_t a[4];
#pragma unroll
    for (int kt = 0; kt < 4; kt++) a[kt] = *(const half8_t*)(hr + kt * 32 + kg * 8);

    f32x4 acc[3];
#pragma unroll
    for (int c = 0; c < 3; c++) acc[c] = (f32x4){0.f, 0.f, 0.f, 0.f};

#pragma unroll
    for (int c = 0; c < 3; c++) {
        const __half* wc = W2t + (size_t)(c * 16 + q) * HID + kg * 8;
#pragma unroll
        for (int kt = 0; kt < 4; kt++) {
            half8_t b = *(const half8_t*)(wc + kt * 32);
            acc[c] = __builtin_amdgcn_mfma_f32_16x16x32_f16(a[kt], b, acc[c], 0, 0, 0);
        }
    }

    int r0 = blockIdx.x * 64 + wid * 16 + kg * 4;
#pragma unroll
    for (int c = 0; c < 3; c++) {
        int col = c * 16 + q;
        if (col < NCLS) {
#pragma unroll
            for (int i = 0; i < 4; i++) {
                int r = r0 + i;
                if (r < M) {
                    int p = __builtin_amdgcn_cvt_pk_fp8_f32(acc[c][i], acc[c][i], 0, false);
                    Z8[(size_t)r * ZPB + col] = (unsigned char)(p & 0xff);
                }
            }
        }
    }
}

// ---------------- agg2 + bias + log_softmax (fp8 Z, 1 line/gather) ----------------
// one 8-lane group per node (32 nodes/block); lanes l>=5 accumulate row padding
// into class-slots 40..63 which the softmax discards.

__global__ __launch_bounds__(256) void k_agg2(const unsigned char* __restrict__ Z8,
                                              const unsigned* __restrict__ eew,
                                              const int* __restrict__ off,
                                              const int* __restrict__ cnt,
                                              const float* __restrict__ dinv,
                                              const float* __restrict__ b2,
                                              float* __restrict__ Out, int n) {
    int tid = threadIdx.x;
    int node = blockIdx.x * 32 + (tid >> 3);
    int l = tid & 7;
    if (node >= n) return;
    float di = dinv[node];
    int start = off[node], ne = cnt[node];

    float acc[8];
    {
        uint2 v = *(const uint2*)(Z8 + (size_t)node * ZPB + l * 8);
        float wv = di * di;
        f32x2 f;
        f = __builtin_amdgcn_cvt_pk_f32_fp8((int)v.x, false);
        acc[0] = f[0] * wv; acc[1] = f[1] * wv;
        f = __builtin_amdgcn_cvt_pk_f32_fp8((int)v.x, true);
        acc[2] = f[0] * wv; acc[3] = f[1] * wv;
        f = __builtin_amdgcn_cvt_pk_f32_fp8((int)v.y, false);
        acc[4] = f[0] * wv; acc[5] = f[1] * wv;
        f = __builtin_amdgcn_cvt_pk_f32_fp8((int)v.y, true);
        acc[6] = f[0] * wv; acc[7] = f[1] * wv;
    }

#pragma unroll 2
    for (int j = 0; j < ne; ++j) {
        unsigned u = eew[start + j];          // group-uniform broadcast load
        int s = (int)(u >> 15);
        float wv = __uint_as_float((u & 0x7FFFu) << 17);
        uint2 v = *(const uint2*)(Z8 + (size_t)s * ZPB + l * 8);
        f32x2 f;
        f = __builtin_amdgcn_cvt_pk_f32_fp8((int)v.x, false);
        acc[0] = fmaf(f[0], wv, acc[0]); acc[1] = fmaf(f[1], wv, acc[1]);
        f = __builtin_amdgcn_cvt_pk_f32_fp8((int)v.x, true);
        acc[2] = fmaf(f[0], wv, acc[2]); acc[3] = fmaf(f[1], wv, acc[3]);
        f = __builtin_amdgcn_cvt_pk_f32_fp8((int)v.y, false);
        acc[4] = fmaf(f[0], wv, acc[4]); acc[5] = fmaf(f[1], wv, acc[5]);
        f = __builtin_amdgcn_cvt_pk_f32_fp8((int)v.y, true);
        acc[6] = fmaf(f[0], wv, acc[6]); acc[7] = fmaf(f[1], wv, acc[7]);
    }

    bool valid = (l < 5);
    float v[8];
    float m = -INFINITY;
#pragma unroll
    for (int i = 0; i < 8; i++) {
        v[i] = valid ? acc[i] + b2[l * 8 + i] : -INFINITY;
        m = fmaxf(m, v[i]);
    }
#pragma unroll
    for (int o = 1; o <= 4; o <<= 1) m = fmaxf(m, __shfl_xor(m, o));
    float ssum = 0.f;
#pragma unroll
    for (int i = 0; i < 8; i++)
        if (valid) ssum += __expf(v[i] - m);
#pragma unroll
    for (int o = 1; o <= 4; o <<= 1) ssum += __shfl_xor(ssum, o);
    float lse = m + logf(ssum);

    if (valid) {
        float4 w0 = make_float4(v[0] - lse, v[1] - lse, v[2] - lse, v[3] - lse);
        float4 w1 = make_float4(v[4] - lse, v[5] - lse, v[6] - lse, v[7] - lse);
        float* op = Out + (size_t)node * NCLS + l * 8;
        *(float4*)op = w0;
        *(float4*)(op + 4) = w1;
    }
}

// ---------------- launch ----------------

extern "C" void kernel_launch(void* const* d_in, const int* in_sizes, int n_in,
                              void* d_out, int out_size, void* d_ws, size_t ws_size,
                              hipStream_t stream) {
    const float* x  = (const float*)d_in[0];
    const int* ei   = (const int*)d_in[1];
    const float* W1 = (const float*)d_in[2];
    const float* b1 = (const float*)d_in[3];
    const float* W2 = (const float*)d_in[4];
    const float* b2 = (const float*)d_in[5];
    float* out = (float*)d_out;

    const int n = in_sizes[0] / FIN;   // 100000
    const int E = in_sizes[1] / 2;     // 1600000
    const int* src = ei;
    const int* dst = ei + E;
    const int nbk = (n + BKT_SZ - 1) >> BKT_SHIFT;  // 196

    char* w = (char*)d_ws;
    auto alloc = [&](size_t bytes) {
        char* p = w;
        w += (bytes + 255) & ~(size_t)255;
        return p;
    };
    int* off     = (int*)alloc((size_t)n * 4);
    int* cnt     = (int*)alloc((size_t)n * 4);
    float* dinv  = (float*)alloc((size_t)n * 4);
    int* bcur    = (int*)alloc((size_t)(nbk + 1) * 4);  // +1: global base ticket
    unsigned* ebkt = (unsigned*)alloc((size_t)nbk * CAP * 4);
    unsigned* eew  = (unsigned*)alloc((size_t)E * 4);
    ushort* wt   = (ushort*)alloc((size_t)FIN * HID * 2);
    __half* w2t  = (__half*)alloc((size_t)48 * HID * 2);
    unsigned char* H8 = (unsigned char*)alloc((size_t)n * HID);
    __half* H2   = (__half*)alloc((size_t)n * HID * 2);
    unsigned char* Z8 = (unsigned char*)alloc((size_t)n * ZPB);

    const int nbkb = (E + CHUNK - 1) / CHUNK;        // bucketize blocks (782)
    const int g1b = (n + 63) / 64;                   // gemm1 blocks (1563)

    // prep: zero bucket cursors + ticket + convert both weight matrices
    k_prep<<<(FIN * HID) / 256, 256, 0, stream>>>(bcur, W1, wt, W2, w2t, nbk);

    // fused: bucketize (independent) overlapped with gemm1
    k_g1bkt<<<nbkb + g1b, 256, 0, stream>>>(x, wt, H8, n, src, dst, E, bcur, ebkt, nbk, nbkb);

    // CSR finalize, bucket-local
    k_cnt<<<nbk, 512, 0, stream>>>(ebkt, bcur, nbk, off, cnt, dinv, n);
    k_place<<<nbk, 512, 0, stream>>>(ebkt, bcur, off, dinv, eew, n);

    // layer 1 aggregation
    k_agg1<<<(n + 15) / 16, 256, 0, stream>>>(H8, eew, off, cnt, dinv, b1, H2, n);

    // layer 2 + log_softmax
    k_gemm2<<<(n + 63) / 64, 256, 0, stream>>>(H2, w2t, Z8, n);
    k_agg2<<<(n + 31) / 32, 256, 0, stream>>>(Z8, eew, off, cnt, dinv, b2, out, n);
}